// Round 2
// baseline (353.611 us; speedup 1.0000x reference)
//
#include <hip/hip_runtime.h>
#include <hip/hip_bf16.h>
#include <math.h>

#define N_PTS 16384
#define DIM   512
#define BM    256               // tile M = N (symmetric)
#define BK    32                // K-step: 64-byte LDS rows -> conflict-free b128 reads
#define NBLK  (N_PTS / BM)      // 64
#define NTRI  (NBLK * (NBLK + 1) / 2)  // 2080
#define KT    (DIM / BK)        // 16 K-tiles
#define HALF_E 4096             // elems per half-tile: 128 rows x 32

typedef __bf16 bf16x8 __attribute__((ext_vector_type(8)));
typedef float  f32x4  __attribute__((ext_vector_type(4)));

#define LGKM0   asm volatile("s_waitcnt lgkmcnt(0)" ::: "memory")
#define VMC4    asm volatile("s_waitcnt vmcnt(4)" ::: "memory")
#define VMC0    asm volatile("s_waitcnt vmcnt(0)" ::: "memory")
#define BARRIER do { asm volatile("" ::: "memory"); __builtin_amdgcn_s_barrier(); asm volatile("" ::: "memory"); } while (0)

__device__ __forceinline__ unsigned int ford(float f) {
    unsigned int u = __float_as_uint(f);
    return (u & 0x80000000u) ? ~u : (u | 0x80000000u);
}
__device__ __forceinline__ unsigned long long pmax64(unsigned long long a, unsigned long long b) {
    return a > b ? a : b;
}

// =====================================================================
// Kernel 1: fp32 -> bf16 convert + init best[] = 0
// =====================================================================
__global__ void k_convert(const float* __restrict__ x,
                          __bf16* __restrict__ xb,
                          unsigned long long* __restrict__ best) {
    int t = blockIdx.x * blockDim.x + threadIdx.x;
    size_t e = (size_t)t * 8;
    float4 f0 = *(const float4*)(x + e);
    float4 f1 = *(const float4*)(x + e + 4);
    bf16x8 v;
    v[0] = (__bf16)f0.x; v[1] = (__bf16)f0.y; v[2] = (__bf16)f0.z; v[3] = (__bf16)f0.w;
    v[4] = (__bf16)f1.x; v[5] = (__bf16)f1.y; v[6] = (__bf16)f1.z; v[7] = (__bf16)f1.w;
    *(bf16x8*)(xb + e) = v;
    if (t < N_PTS) best[t] = 0ull;
}

// =====================================================================
// Kernel 2: 256x256 upper-tri tiles, 8 waves (2M x 4N), BK=32, 4-buffer
// counted-vmcnt pipeline (T3+T4), setprio (T5), fused row/col argmax.
// =====================================================================
__global__ __launch_bounds__(512, 2)
void k_gemm_argmax(const __bf16* __restrict__ xb,
                   unsigned long long* __restrict__ best) {
    __shared__ __bf16 As[4][2 * HALF_E];   // [buf][half*4096 + row*32 + col]
    __shared__ __bf16 Bs[4][2 * HALF_E];

    // triangle decode: t = bn*(bn+1)/2 + bm, bm <= bn
    int t = (int)blockIdx.x;
    int bn = (int)((sqrtf(8.0f * (float)t + 1.0f) - 1.0f) * 0.5f);
    while ((bn + 1) * (bn + 2) / 2 <= t) ++bn;
    while (bn * (bn + 1) / 2 > t) --bn;
    int bm = t - bn * (bn + 1) / 2;

    const int tid  = (int)threadIdx.x;
    const int lane = tid & 63;
    const int wid  = tid >> 6;       // 0..7
    const int wr   = wid >> 2;       // 0..1 -> 128-row band
    const int wc   = wid & 3;        // 0..3 -> 64-col band
    const int lr   = lane & 15;
    const int lk   = lane >> 4;

    const int arow0 = bm * BM;
    const int brow0 = bn * BM;

    // staging: thread tid covers 16B chunk tid of an 8KB half-tile
    // row_local = tid>>2 (0..127), k-chunk = tid&3 (8 elems each)
    const __bf16* gA = xb + (size_t)(arow0 + (tid >> 2)) * DIM + (tid & 3) * 8;
    const __bf16* gB = xb + (size_t)(brow0 + (tid >> 2)) * DIM + (tid & 3) * 8;
    const int wbase = wid * 512;     // wave's 1KB slice within a half

    auto stage = [&](const __bf16* gbase, __bf16* lbuf, int kt, int h) {
        const __bf16* g = gbase + (size_t)(h * 128) * DIM + kt * BK;
        __bf16* l = lbuf + h * HALF_E + wbase;
        __builtin_amdgcn_global_load_lds(
            (const __attribute__((address_space(1))) void*)g,
            (__attribute__((address_space(3))) void*)l, 16, 0, 0);
    };

    f32x4 acc[8][4] = {};

    // ---- prologue: stage K-tiles 0 and 1 (8 half-tiles, 8 loads/wave) ----
    stage(gA, As[0], 0, 0); stage(gA, As[0], 0, 1);
    stage(gB, Bs[0], 0, 0); stage(gB, Bs[0], 0, 1);
    stage(gA, As[1], 1, 0); stage(gA, As[1], 1, 1);
    stage(gB, Bs[1], 1, 0); stage(gB, Bs[1], 1, 1);

    // ds_read bases (no swizzle needed: 64-B rows are bank-conflict-optimal)
    const int aoff = wr * HALF_E + lr * 32 + lk * 8;                 // + (g*4+m)*512
    const int boff = (wc >> 1) * HALF_E + ((wc & 1) * 64 + lr) * 32 + lk * 8;  // + n*512

    VMC4;        // K-tile 0 fully landed (K-tile 1's 4 loads may be in flight)
    BARRIER;

    for (int i = 0; i < 8; ++i) {
        const int t0 = 2 * i, t1 = 2 * i + 1;
        const __bf16* Ab0 = As[t0 & 3]; const __bf16* Bb0 = Bs[t0 & 3];
        const __bf16* Ab1 = As[t1 & 3]; const __bf16* Bb1 = Bs[t1 & 3];
        __bf16* Asa = As[(t0 + 2) & 3]; __bf16* Bsa = Bs[(t0 + 2) & 3];
        __bf16* Asb = As[(t1 + 2) & 3]; __bf16* Bsb = Bs[(t1 + 2) & 3];
        const bool stg = (i < 7);

        bf16x8 af[4], bfr[4];

        // ---------- phase 1: K-tile t0, m-group 0 ----------
#pragma unroll
        for (int m = 0; m < 4; ++m) af[m] = *(const bf16x8*)(Ab0 + aoff + m * 512);
#pragma unroll
        for (int n = 0; n < 4; ++n) bfr[n] = *(const bf16x8*)(Bb0 + boff + n * 512);
        if (stg) { stage(gA, Asa, t0 + 2, 0); stage(gA, Asa, t0 + 2, 1); }
        BARRIER; LGKM0;
        __builtin_amdgcn_s_setprio(1);
#pragma unroll
        for (int m = 0; m < 4; ++m)
#pragma unroll
            for (int n = 0; n < 4; ++n)
                acc[m][n] = __builtin_amdgcn_mfma_f32_16x16x32_bf16(af[m], bfr[n], acc[m][n], 0, 0, 0);
        __builtin_amdgcn_s_setprio(0);
        BARRIER;

        // ---------- phase 2: K-tile t0, m-group 1 ----------
#pragma unroll
        for (int m = 0; m < 4; ++m) af[m] = *(const bf16x8*)(Ab0 + aoff + 2048 + m * 512);
        if (stg) { stage(gB, Bsa, t0 + 2, 0); stage(gB, Bsa, t0 + 2, 1); }
        BARRIER; LGKM0;
        __builtin_amdgcn_s_setprio(1);
#pragma unroll
        for (int m = 0; m < 4; ++m)
#pragma unroll
            for (int n = 0; n < 4; ++n)
                acc[4 + m][n] = __builtin_amdgcn_mfma_f32_16x16x32_bf16(af[m], bfr[n], acc[4 + m][n], 0, 0, 0);
        __builtin_amdgcn_s_setprio(0);
        if (stg) { VMC4; } else { VMC0; }   // K-tile t1 landed; then barrier -> all waves' slices visible
        BARRIER;

        // ---------- phase 3: K-tile t1, m-group 0 ----------
#pragma unroll
        for (int m = 0; m < 4; ++m) af[m] = *(const bf16x8*)(Ab1 + aoff + m * 512);
#pragma unroll
        for (int n = 0; n < 4; ++n) bfr[n] = *(const bf16x8*)(Bb1 + boff + n * 512);
        if (stg) { stage(gA, Asb, t1 + 2, 0); stage(gA, Asb, t1 + 2, 1); }
        BARRIER; LGKM0;
        __builtin_amdgcn_s_setprio(1);
#pragma unroll
        for (int m = 0; m < 4; ++m)
#pragma unroll
            for (int n = 0; n < 4; ++n)
                acc[m][n] = __builtin_amdgcn_mfma_f32_16x16x32_bf16(af[m], bfr[n], acc[m][n], 0, 0, 0);
        __builtin_amdgcn_s_setprio(0);
        BARRIER;

        // ---------- phase 4: K-tile t1, m-group 1 ----------
#pragma unroll
        for (int m = 0; m < 4; ++m) af[m] = *(const bf16x8*)(Ab1 + aoff + 2048 + m * 512);
        if (stg) { stage(gB, Bsb, t1 + 2, 0); stage(gB, Bsb, t1 + 2, 1); }
        BARRIER; LGKM0;
        __builtin_amdgcn_s_setprio(1);
#pragma unroll
        for (int m = 0; m < 4; ++m)
#pragma unroll
            for (int n = 0; n < 4; ++n)
                acc[4 + m][n] = __builtin_amdgcn_mfma_f32_16x16x32_bf16(af[m], bfr[n], acc[4 + m][n], 0, 0, 0);
        __builtin_amdgcn_s_setprio(0);
        VMC4;                               // K-tile t0+2 landed before next iteration's reads
        BARRIER;
    }

    // ---- epilogue: fused argmax, packed (ford(v)<<32 | ~idx) u64 max ----
    // C/D layout: col = lane&15 (lr), row = lk*4 + reg(j)

    // ROW view: rows of bm-block, reduce over this tile's 64 cols (wave's band)
#pragma unroll
    for (int m = 0; m < 8; ++m) {
#pragma unroll
        for (int j = 0; j < 4; ++j) {
            int grow = arow0 + wr * 128 + m * 16 + lk * 4 + j;
            float v = -3.0e38f; int c = 0;
#pragma unroll
            for (int n = 0; n < 4; ++n) {
                int gcol = brow0 + wc * 64 + n * 16 + lr;
                float val = acc[m][n][j];
                if (gcol == grow) val = -1.0f;
                if (val > v || (val == v && gcol < c)) { v = val; c = gcol; }
            }
            unsigned long long p = ((unsigned long long)ford(v) << 32)
                                 | (unsigned)(0xFFFFFFFFu - (unsigned)c);
            p = pmax64(p, __shfl_xor(p, 1, 64));
            p = pmax64(p, __shfl_xor(p, 2, 64));
            p = pmax64(p, __shfl_xor(p, 4, 64));
            p = pmax64(p, __shfl_xor(p, 8, 64));
            if (lr == 0) atomicMax(best + grow, p);
        }
    }

    // COL view (symmetry): rows of bn-block, reduce over the tile's 128 A-rows
#pragma unroll
    for (int n = 0; n < 4; ++n) {
        int gcol = brow0 + wc * 64 + n * 16 + lr;
        float v = -3.0e38f; int c = 0;
#pragma unroll
        for (int m = 0; m < 8; ++m) {
#pragma unroll
            for (int j = 0; j < 4; ++j) {
                int grow = arow0 + wr * 128 + m * 16 + lk * 4 + j;
                float val = acc[m][n][j];
                if (grow == gcol) val = -1.0f;
                if (val > v || (val == v && grow < c)) { v = val; c = grow; }
            }
        }
        unsigned long long p = ((unsigned long long)ford(v) << 32)
                             | (unsigned)(0xFFFFFFFFu - (unsigned)c);
        p = pmax64(p, __shfl_xor(p, 16, 64));
        p = pmax64(p, __shfl_xor(p, 32, 64));
        if (lk == 0) atomicMax(best + gcol, p);
    }
}

// =====================================================================
// Kernel 3: per-row fp32 loss term
// =====================================================================
__global__ void k_rowloss(const float* __restrict__ x,
                          const unsigned long long* __restrict__ best,
                          float* __restrict__ rowloss) {
    int wave = (int)threadIdx.x >> 6, lane = (int)threadIdx.x & 63;
    int r = (int)blockIdx.x * 4 + wave;
    unsigned long long p = best[r];
    int nb = (int)(0xFFFFFFFFu - (unsigned)(p & 0xFFFFFFFFull));
    const float4* xr = (const float4*)(x + (size_t)r  * DIM);
    const float4* xn = (const float4*)(x + (size_t)nb * DIM);
    float s = 0.f;
#pragma unroll
    for (int i = 0; i < 2; ++i) {
        float4 a = xr[lane * 2 + i];
        float4 b = xn[lane * 2 + i];
        float d0 = a.x - b.x + 1e-6f;
        float d1 = a.y - b.y + 1e-6f;
        float d2 = a.z - b.z + 1e-6f;
        float d3 = a.w - b.w + 1e-6f;
        s = fmaf(d0, d0, s); s = fmaf(d1, d1, s);
        s = fmaf(d2, d2, s); s = fmaf(d3, d3, s);
    }
#pragma unroll
    for (int m = 1; m < 64; m <<= 1) s += __shfl_xor(s, m, 64);
    if (lane == 0) rowloss[r] = logf(sqrtf(s) + 1e-8f);
}

// =====================================================================
// Kernel 4: deterministic single-block reduction -> scalar
// =====================================================================
__global__ void k_reduce(const float* __restrict__ rowloss, float* __restrict__ out) {
    __shared__ float sm[256];
    float s = 0.f;
    for (int i = (int)threadIdx.x; i < N_PTS; i += 256) s += rowloss[i];
    sm[threadIdx.x] = s;
    __syncthreads();
    for (int st = 128; st > 0; st >>= 1) {
        if ((int)threadIdx.x < st) sm[threadIdx.x] += sm[threadIdx.x + st];
        __syncthreads();
    }
    if (threadIdx.x == 0) out[0] = -0.1f * sm[0] / (float)N_PTS;
}

extern "C" void kernel_launch(void* const* d_in, const int* in_sizes, int n_in,
                              void* d_out, int out_size, void* d_ws, size_t ws_size,
                              hipStream_t stream) {
    const float* x = (const float*)d_in[0];
    float* out = (float*)d_out;
    char* ws = (char*)d_ws;

    __bf16* xb = (__bf16*)ws;
    unsigned long long* best = (unsigned long long*)(ws + (size_t)N_PTS * DIM * 2);
    float* rowloss = (float*)(ws + (size_t)N_PTS * DIM * 2 + (size_t)N_PTS * 8);

    k_convert<<<dim3(4096), dim3(256), 0, stream>>>(x, xb, best);
    k_gemm_argmax<<<dim3(NTRI), dim3(512), 0, stream>>>(xb, best);
    k_rowloss<<<dim3(N_PTS / 4), dim3(256), 0, stream>>>(x, best, rowloss);
    k_reduce<<<dim3(1), dim3(256), 0, stream>>>(rowloss, out);
}

// Round 3
// 266.501 us; speedup vs baseline: 1.3269x; 1.3269x over previous
//
#include <hip/hip_runtime.h>
#include <hip/hip_bf16.h>
#include <math.h>

#define N_PTS 16384
#define DIM   512
#define BM    128               // tile M = N
#define BK    32                // 64-B LDS rows -> bank-conflict-free ds_read_b128
#define NBLK  (N_PTS / BM)      // 128
#define NTRI  (NBLK * (NBLK + 1) / 2)  // 8256
#define TILE_E (BM * BK)        // 4096 elems = 8 KB per operand tile

typedef __bf16 bf16x8 __attribute__((ext_vector_type(8)));
typedef float  f32x4  __attribute__((ext_vector_type(4)));

#define VMC0    asm volatile("s_waitcnt vmcnt(0)" ::: "memory")
#define BARRIER do { __builtin_amdgcn_s_barrier(); } while (0)

__device__ __forceinline__ unsigned int ford(float f) {
    unsigned int u = __float_as_uint(f);
    return (u & 0x80000000u) ? ~u : (u | 0x80000000u);
}
__device__ __forceinline__ unsigned long long pmax64(unsigned long long a, unsigned long long b) {
    return a > b ? a : b;
}

// =====================================================================
// Kernel 1: fp32 -> bf16 convert + init best[] = 0
// =====================================================================
__global__ void k_convert(const float* __restrict__ x,
                          __bf16* __restrict__ xb,
                          unsigned long long* __restrict__ best) {
    int t = blockIdx.x * blockDim.x + threadIdx.x;
    size_t e = (size_t)t * 8;
    float4 f0 = *(const float4*)(x + e);
    float4 f1 = *(const float4*)(x + e + 4);
    bf16x8 v;
    v[0] = (__bf16)f0.x; v[1] = (__bf16)f0.y; v[2] = (__bf16)f0.z; v[3] = (__bf16)f0.w;
    v[4] = (__bf16)f1.x; v[5] = (__bf16)f1.y; v[6] = (__bf16)f1.z; v[7] = (__bf16)f1.w;
    *(bf16x8*)(xb + e) = v;
    if (t < N_PTS) best[t] = 0ull;
}

// =====================================================================
// Kernel 2: 128x128 upper-tri tiles, 4 waves (2x2), BK=32, double-buffer
// 2-phase pipeline (stage next before compute cur, 1 barrier/K-step),
// fused row/col argmax epilogue.
// =====================================================================
__global__ void k_gemm_argmax(const __bf16* __restrict__ xb,
                              unsigned long long* __restrict__ best) {
    __shared__ __bf16 As0[TILE_E], Bs0[TILE_E];
    __shared__ __bf16 As1[TILE_E], Bs1[TILE_E];

    // triangle decode: t = bn*(bn+1)/2 + bm, bm <= bn
    int t = (int)blockIdx.x;
    int bn = (int)((sqrtf(8.0f * (float)t + 1.0f) - 1.0f) * 0.5f);
    while ((bn + 1) * (bn + 2) / 2 <= t) ++bn;
    while (bn * (bn + 1) / 2 > t) --bn;
    int bm = t - bn * (bn + 1) / 2;

    const int tid  = (int)threadIdx.x;
    const int lane = tid & 63;
    const int wave = tid >> 6;       // 0..3
    const int wr   = wave >> 1;      // 0/1 -> 64-row band
    const int wc   = wave & 1;       // 0/1 -> 64-col band
    const int lr   = lane & 15;
    const int lk   = lane >> 4;

    const int arow0 = bm * BM;
    const int brow0 = bn * BM;

    // staging geometry: 8KB tile = 512 x 16B chunks; thread covers chunks
    // {tid, 256+tid}. chunk ci: row = ci>>2 (64B = 4 chunks/row), col8 = ci&3.
    const __bf16* gA0 = xb + (size_t)(arow0 + (tid >> 2)) * DIM + (tid & 3) * 8;
    const __bf16* gA1 = xb + (size_t)(arow0 + 64 + (tid >> 2)) * DIM + (tid & 3) * 8;
    const __bf16* gB0 = xb + (size_t)(brow0 + (tid >> 2)) * DIM + (tid & 3) * 8;
    const __bf16* gB1 = xb + (size_t)(brow0 + 64 + (tid >> 2)) * DIM + (tid & 3) * 8;
    const int cb0 = (tid & ~63) * 8;          // wave-uniform LDS elem base, chunk set 0
    const int cb1 = (256 + (tid & ~63)) * 8;  // chunk set 1

#define STAGE(Adst, Bdst, kt)                                                        \
    do {                                                                             \
        int ko = (kt) * BK;                                                          \
        __builtin_amdgcn_global_load_lds(                                            \
            (const __attribute__((address_space(1))) void*)(gA0 + ko),               \
            (__attribute__((address_space(3))) void*)((Adst) + cb0), 16, 0, 0);      \
        __builtin_amdgcn_global_load_lds(                                            \
            (const __attribute__((address_space(1))) void*)(gA1 + ko),               \
            (__attribute__((address_space(3))) void*)((Adst) + cb1), 16, 0, 0);      \
        __builtin_amdgcn_global_load_lds(                                            \
            (const __attribute__((address_space(1))) void*)(gB0 + ko),               \
            (__attribute__((address_space(3))) void*)((Bdst) + cb0), 16, 0, 0);      \
        __builtin_amdgcn_global_load_lds(                                            \
            (const __attribute__((address_space(1))) void*)(gB1 + ko),               \
            (__attribute__((address_space(3))) void*)((Bdst) + cb1), 16, 0, 0);      \
    } while (0)

    // fragment read offsets (elems): row*32 + lk*8
    const int aoff = (wr * 64 + lr) * BK + lk * 8;   // + m*16*BK
    const int boff = (wc * 64 + lr) * BK + lk * 8;   // + n*16*BK

    f32x4 acc[4][4] = {};
    bf16x8 af[4], bfr[4];

#define COMPUTE(Asrc, Bsrc)                                                          \
    do {                                                                             \
        _Pragma("unroll")                                                            \
        for (int m = 0; m < 4; ++m) af[m] = *(const bf16x8*)((Asrc) + aoff + m * 16 * BK); \
        _Pragma("unroll")                                                            \
        for (int n = 0; n < 4; ++n) bfr[n] = *(const bf16x8*)((Bsrc) + boff + n * 16 * BK); \
        __builtin_amdgcn_s_setprio(1);                                               \
        _Pragma("unroll")                                                            \
        for (int m = 0; m < 4; ++m)                                                  \
            _Pragma("unroll")                                                        \
            for (int n = 0; n < 4; ++n)                                              \
                acc[m][n] = __builtin_amdgcn_mfma_f32_16x16x32_bf16(af[m], bfr[n], acc[m][n], 0, 0, 0); \
        __builtin_amdgcn_s_setprio(0);                                               \
    } while (0)

    // ---- prologue: stage K-step 0 into buffer 0 ----
    STAGE(As0, Bs0, 0);
    VMC0;
    BARRIER;

    // ---- main loop: 16 K-steps, unroll x2 over static buffers ----
    for (int i = 0; i < 8; ++i) {
        STAGE(As1, Bs1, 2 * i + 1);       // prefetch odd step
        COMPUTE(As0, Bs0);                // compute even step (hides stage)
        VMC0;                             // odd-step loads landed
        BARRIER;                          // all waves done reading buf0 + loads visible
        if (i < 7) STAGE(As0, Bs0, 2 * i + 2);
        COMPUTE(As1, Bs1);
        if (i < 7) { VMC0; BARRIER; }
    }

    // ---- epilogue: fused argmax, packed (ford(v)<<32 | ~idx) u64 max ----
    // C/D layout: col = lane&15 (lr), row = lk*4 + reg(j)

    // ROW view: rows of bm-block vs this tile's 64 cols in wave's band
#pragma unroll
    for (int m = 0; m < 4; ++m) {
#pragma unroll
        for (int j = 0; j < 4; ++j) {
            int grow = arow0 + wr * 64 + m * 16 + lk * 4 + j;
            float v = -3.0e38f; int c = 0;
#pragma unroll
            for (int n = 0; n < 4; ++n) {
                int gcol = brow0 + wc * 64 + n * 16 + lr;
                float val = acc[m][n][j];
                if (gcol == grow) val = -1.0f;
                if (val > v || (val == v && gcol < c)) { v = val; c = gcol; }
            }
            unsigned long long p = ((unsigned long long)ford(v) << 32)
                                 | (unsigned)(0xFFFFFFFFu - (unsigned)c);
            p = pmax64(p, __shfl_xor(p, 1, 64));
            p = pmax64(p, __shfl_xor(p, 2, 64));
            p = pmax64(p, __shfl_xor(p, 4, 64));
            p = pmax64(p, __shfl_xor(p, 8, 64));
            if (lr == 0) atomicMax(best + grow, p);
        }
    }

    // COL view (symmetry): rows of bn-block vs the tile's 64 A-rows in band
#pragma unroll
    for (int n = 0; n < 4; ++n) {
        int gcol = brow0 + wc * 64 + n * 16 + lr;
        float v = -3.0e38f; int c = 0;
#pragma unroll
        for (int m = 0; m < 4; ++m) {
#pragma unroll
            for (int j = 0; j < 4; ++j) {
                int grow = arow0 + wr * 64 + m * 16 + lk * 4 + j;
                float val = acc[m][n][j];
                if (grow == gcol) val = -1.0f;
                if (val > v || (val == v && grow < c)) { v = val; c = grow; }
            }
        }
        unsigned long long p = ((unsigned long long)ford(v) << 32)
                             | (unsigned)(0xFFFFFFFFu - (unsigned)c);
        p = pmax64(p, __shfl_xor(p, 16, 64));
        p = pmax64(p, __shfl_xor(p, 32, 64));
        if (lk == 0) atomicMax(best + gcol, p);
    }
#undef STAGE
#undef COMPUTE
}

// =====================================================================
// Kernel 3: per-row fp32 loss term
// =====================================================================
__global__ void k_rowloss(const float* __restrict__ x,
                          const unsigned long long* __restrict__ best,
                          float* __restrict__ rowloss) {
    int wave = (int)threadIdx.x >> 6, lane = (int)threadIdx.x & 63;
    int r = (int)blockIdx.x * 4 + wave;
    unsigned long long p = best[r];
    int nb = (int)(0xFFFFFFFFu - (unsigned)(p & 0xFFFFFFFFull));
    const float4* xr = (const float4*)(x + (size_t)r  * DIM);
    const float4* xn = (const float4*)(x + (size_t)nb * DIM);
    float s = 0.f;
#pragma unroll
    for (int i = 0; i < 2; ++i) {
        float4 a = xr[lane * 2 + i];
        float4 b = xn[lane * 2 + i];
        float d0 = a.x - b.x + 1e-6f;
        float d1 = a.y - b.y + 1e-6f;
        float d2 = a.z - b.z + 1e-6f;
        float d3 = a.w - b.w + 1e-6f;
        s = fmaf(d0, d0, s); s = fmaf(d1, d1, s);
        s = fmaf(d2, d2, s); s = fmaf(d3, d3, s);
    }
#pragma unroll
    for (int m = 1; m < 64; m <<= 1) s += __shfl_xor(s, m, 64);
    if (lane == 0) rowloss[r] = logf(sqrtf(s) + 1e-8f);
}

// =====================================================================
// Kernel 4: deterministic single-block reduction -> scalar
// =====================================================================
__global__ void k_reduce(const float* __restrict__ rowloss, float* __restrict__ out) {
    __shared__ float sm[256];
    float s = 0.f;
    for (int i = (int)threadIdx.x; i < N_PTS; i += 256) s += rowloss[i];
    sm[threadIdx.x] = s;
    __syncthreads();
    for (int st = 128; st > 0; st >>= 1) {
        if ((int)threadIdx.x < st) sm[threadIdx.x] += sm[threadIdx.x + st];
        __syncthreads();
    }
    if (threadIdx.x == 0) out[0] = -0.1f * sm[0] / (float)N_PTS;
}

extern "C" void kernel_launch(void* const* d_in, const int* in_sizes, int n_in,
                              void* d_out, int out_size, void* d_ws, size_t ws_size,
                              hipStream_t stream) {
    const float* x = (const float*)d_in[0];
    float* out = (float*)d_out;
    char* ws = (char*)d_ws;

    __bf16* xb = (__bf16*)ws;
    unsigned long long* best = (unsigned long long*)(ws + (size_t)N_PTS * DIM * 2);
    float* rowloss = (float*)(ws + (size_t)N_PTS * DIM * 2 + (size_t)N_PTS * 8);

    k_convert<<<dim3(4096), dim3(256), 0, stream>>>(x, xb, best);
    k_gemm_argmax<<<dim3(NTRI), dim3(256), 0, stream>>>(xb, best);
    k_rowloss<<<dim3(N_PTS / 4), dim3(256), 0, stream>>>(x, best, rowloss);
    k_reduce<<<dim3(1), dim3(256), 0, stream>>>(rowloss, out);
}

// Round 4
// 261.836 us; speedup vs baseline: 1.3505x; 1.0178x over previous
//
#include <hip/hip_runtime.h>
#include <hip/hip_bf16.h>
#include <math.h>

#define N_PTS 16384
#define DIM   512
#define BM    128               // tile M = N
#define BK    64                // i8: 64-byte LDS rows
#define NBLK  (N_PTS / BM)      // 128
#define NTRI  (NBLK * (NBLK + 1) / 2)  // 8256
#define TILE_B (BM * BK)        // 8192 bytes per operand tile
#define QSCALE 23.0f

typedef int i32x4  __attribute__((ext_vector_type(4)));
typedef int i32x16 __attribute__((ext_vector_type(16)));

#define VMC0    asm volatile("s_waitcnt vmcnt(0)" ::: "memory")
#define BARRIER do { __builtin_amdgcn_s_barrier(); } while (0)

__device__ __forceinline__ unsigned long long pmax64(unsigned long long a, unsigned long long b) {
    return a > b ? a : b;
}
// order-preserving i32 -> u32
__device__ __forceinline__ unsigned int iord(int v) { return (unsigned)v ^ 0x80000000u; }

// =====================================================================
// Kernel 1: fp32 -> int8 quantize (q = rint(23*x), |x|<5.5 -> no clip)
//           + init best[] = 0
// =====================================================================
__global__ void k_quant(const float* __restrict__ x,
                        char* __restrict__ xq,
                        unsigned long long* __restrict__ best) {
    int t = blockIdx.x * blockDim.x + threadIdx.x;
    size_t e = (size_t)t * 8;
    float4 f0 = *(const float4*)(x + e);
    float4 f1 = *(const float4*)(x + e + 4);
    auto q8 = [](float v) -> int {
        return (int)rintf(fminf(fmaxf(v * QSCALE, -127.0f), 127.0f));
    };
    int lo = (q8(f0.x) & 255) | ((q8(f0.y) & 255) << 8)
           | ((q8(f0.z) & 255) << 16) | ((q8(f0.w) & 255) << 24);
    int hi = (q8(f1.x) & 255) | ((q8(f1.y) & 255) << 8)
           | ((q8(f1.z) & 255) << 16) | ((q8(f1.w) & 255) << 24);
    int2 o; o.x = lo; o.y = hi;
    *(int2*)(xq + e) = o;
    if (t < N_PTS) best[t] = 0ull;
}

// =====================================================================
// Kernel 2: S = Xq * Xq^T (int32 exact) on upper-tri 128x128 tiles,
// 4 waves (2x2, 64x64/wave), 32x32x32 i8 MFMA, BK=64, double-buffer
// 2-phase pipeline, XOR-swizzled LDS (chunk q ^= row&3, inverse-swz src),
// fused row/col argmax epilogue. T1 XCD swizzle on blockIdx.
// =====================================================================
__global__ void k_gemm_argmax(const char* __restrict__ xq,
                              unsigned long long* __restrict__ best) {
    __shared__ __align__(16) char As0[TILE_B], Bs0[TILE_B];
    __shared__ __align__(16) char As1[TILE_B], Bs1[TILE_B];

    // T1: XCD-aware bijective swizzle (8256 % 8 == 0)
    int t0i = (int)blockIdx.x;
    int t = (t0i & 7) * (NTRI / 8) + (t0i >> 3);

    // triangle decode: t = bn*(bn+1)/2 + bm, bm <= bn
    int bn = (int)((sqrtf(8.0f * (float)t + 1.0f) - 1.0f) * 0.5f);
    while ((bn + 1) * (bn + 2) / 2 <= t) ++bn;
    while (bn * (bn + 1) / 2 > t) --bn;
    int bm = t - bn * (bn + 1) / 2;

    const int tid  = (int)threadIdx.x;
    const int lane = tid & 63;
    const int wave = tid >> 6;       // 0..3
    const int wr   = wave >> 1;      // 0/1 -> 64-row band
    const int wc   = wave & 1;       // 0/1 -> 64-col band
    const int l31  = lane & 31;
    const int h    = lane >> 5;      // k-half of A/B frag; row-group of C
    const int l3   = lane & 3;

    const int arow0 = bm * BM;
    const int brow0 = bn * BM;

    // ---- staging geometry: 8KB tile = 512 x 16B chunks, thread covers
    // chunks {tid, 256+tid}. chunk ci: row = ci>>2, p = ci&3.
    // LDS is linear; SOURCE is inverse-swizzled: col16 = p ^ (row&3).
    {
    }
    const int srow  = tid >> 2;            // 0..63 (set0); set1 = +64 (same row&3)
    const int scol16 = (tid & 3) ^ (srow & 3);
    const char* gA0 = xq + (size_t)(arow0 + srow)      * DIM + scol16 * 16;
    const char* gA1 = xq + (size_t)(arow0 + 64 + srow) * DIM + scol16 * 16;
    const char* gB0 = xq + (size_t)(brow0 + srow)      * DIM + scol16 * 16;
    const char* gB1 = xq + (size_t)(brow0 + 64 + srow) * DIM + scol16 * 16;
    const int cb0 = (tid & ~63) * 16;          // wave-uniform LDS byte base, set 0
    const int cb1 = (256 + (tid & ~63)) * 16;  // set 1

#define STAGE(Adst, Bdst, kt)                                                        \
    do {                                                                             \
        int ko = (kt) * BK;                                                          \
        __builtin_amdgcn_global_load_lds(                                            \
            (const __attribute__((address_space(1))) void*)(gA0 + ko),               \
            (__attribute__((address_space(3))) void*)((Adst) + cb0), 16, 0, 0);      \
        __builtin_amdgcn_global_load_lds(                                            \
            (const __attribute__((address_space(1))) void*)(gA1 + ko),               \
            (__attribute__((address_space(3))) void*)((Adst) + cb1), 16, 0, 0);      \
        __builtin_amdgcn_global_load_lds(                                            \
            (const __attribute__((address_space(1))) void*)(gB0 + ko),               \
            (__attribute__((address_space(3))) void*)((Bdst) + cb0), 16, 0, 0);      \
        __builtin_amdgcn_global_load_lds(                                            \
            (const __attribute__((address_space(1))) void*)(gB1 + ko),               \
            (__attribute__((address_space(3))) void*)((Bdst) + cb1), 16, 0, 0);      \
    } while (0)

    // ---- fragment read byte offsets (swizzled): row*64 + ((q ^ (row&3))<<4)
    // A frag (32x32x32 i8): row = wr*64 + m*32 + l31, k-chunk q = s*2 + h
    // row&3 == l3 (bases are multiples of 4)
    int aoff[2], boff[2];
#pragma unroll
    for (int m = 0; m < 2; ++m)
        aoff[m] = (wr * 64 + m * 32 + l31) * 64 + ((h ^ l3) << 4);   // s=0; s=1: ^32
#pragma unroll
    for (int n = 0; n < 2; ++n)
        boff[n] = (wc * 64 + n * 32 + l31) * 64 + ((h ^ l3) << 4);

    i32x16 acc[2][2] = {};

#define COMPUTE(Asrc, Bsrc)                                                          \
    do {                                                                             \
        i32x4 a0 = *(const i32x4*)((Asrc) + aoff[0]);                                \
        i32x4 a1 = *(const i32x4*)((Asrc) + aoff[1]);                                \
        i32x4 b0 = *(const i32x4*)((Bsrc) + boff[0]);                                \
        i32x4 b1 = *(const i32x4*)((Bsrc) + boff[1]);                                \
        i32x4 a2 = *(const i32x4*)((Asrc) + (aoff[0] ^ 32));                         \
        i32x4 a3 = *(const i32x4*)((Asrc) + (aoff[1] ^ 32));                         \
        i32x4 b2 = *(const i32x4*)((Bsrc) + (boff[0] ^ 32));                         \
        i32x4 b3 = *(const i32x4*)((Bsrc) + (boff[1] ^ 32));                         \
        __builtin_amdgcn_s_setprio(1);                                               \
        acc[0][0] = __builtin_amdgcn_mfma_i32_32x32x32_i8(a0, b0, acc[0][0], 0, 0, 0); \
        acc[0][1] = __builtin_amdgcn_mfma_i32_32x32x32_i8(a0, b1, acc[0][1], 0, 0, 0); \
        acc[1][0] = __builtin_amdgcn_mfma_i32_32x32x32_i8(a1, b0, acc[1][0], 0, 0, 0); \
        acc[1][1] = __builtin_amdgcn_mfma_i32_32x32x32_i8(a1, b1, acc[1][1], 0, 0, 0); \
        acc[0][0] = __builtin_amdgcn_mfma_i32_32x32x32_i8(a2, b2, acc[0][0], 0, 0, 0); \
        acc[0][1] = __builtin_amdgcn_mfma_i32_32x32x32_i8(a2, b3, acc[0][1], 0, 0, 0); \
        acc[1][0] = __builtin_amdgcn_mfma_i32_32x32x32_i8(a3, b2, acc[1][0], 0, 0, 0); \
        acc[1][1] = __builtin_amdgcn_mfma_i32_32x32x32_i8(a3, b3, acc[1][1], 0, 0, 0); \
        __builtin_amdgcn_s_setprio(0);                                               \
    } while (0)

    // ---- prologue: stage K-tile 0 ----
    STAGE(As0, Bs0, 0);
    VMC0;
    BARRIER;

    // ---- main loop: 8 K-tiles of 64, unroll x2 over static buffers ----
    for (int i = 0; i < 4; ++i) {
        STAGE(As1, Bs1, 2 * i + 1);
        COMPUTE(As0, Bs0);
        VMC0;
        BARRIER;
        if (i < 3) STAGE(As0, Bs0, 2 * i + 2);
        COMPUTE(As1, Bs1);
        if (i < 3) { VMC0; BARRIER; }
    }

    // ---- epilogue: fused argmax over exact i32 dots ----
    // C/D 32x32 layout: col = lane&31, row = (r&3) + 8*(r>>2) + 4*(lane>>5)

    // ROW view: rows of bm-block vs this wave's 64 cols
#pragma unroll
    for (int m = 0; m < 2; ++m) {
#pragma unroll
        for (int r = 0; r < 16; ++r) {
            int grow = arow0 + wr * 64 + m * 32 + (r & 3) + 8 * (r >> 2) + 4 * h;
            int gcol0 = brow0 + wc * 64 + l31;
            int gcol1 = gcol0 + 32;
            int v0 = (gcol0 == grow) ? (int)0x80000000 : acc[m][0][r];
            int v1 = (gcol1 == grow) ? (int)0x80000000 : acc[m][1][r];
            unsigned long long p0 = ((unsigned long long)iord(v0) << 32)
                                  | (unsigned)(0xFFFFFFFFu - (unsigned)gcol0);
            unsigned long long p1 = ((unsigned long long)iord(v1) << 32)
                                  | (unsigned)(0xFFFFFFFFu - (unsigned)gcol1);
            unsigned long long p = pmax64(p0, p1);
            p = pmax64(p, __shfl_xor(p, 1, 64));
            p = pmax64(p, __shfl_xor(p, 2, 64));
            p = pmax64(p, __shfl_xor(p, 4, 64));
            p = pmax64(p, __shfl_xor(p, 8, 64));
            p = pmax64(p, __shfl_xor(p, 16, 64));
            if (l31 == 0) atomicMax(best + grow, p);
        }
    }

    // COL view (symmetry): cols of bn-block vs this wave's 64 rows
#pragma unroll
    for (int n = 0; n < 2; ++n) {
        int gcol = brow0 + wc * 64 + n * 32 + l31;
        unsigned long long p = 0ull;
#pragma unroll
        for (int m = 0; m < 2; ++m) {
#pragma unroll
            for (int r = 0; r < 16; ++r) {
                int grow = arow0 + wr * 64 + m * 32 + (r & 3) + 8 * (r >> 2) + 4 * h;
                int v = (grow == gcol) ? (int)0x80000000 : acc[m][n][r];
                unsigned long long q = ((unsigned long long)iord(v) << 32)
                                     | (unsigned)(0xFFFFFFFFu - (unsigned)grow);
                p = pmax64(p, q);
            }
        }
        p = pmax64(p, __shfl_xor(p, 32, 64));
        if (h == 0) atomicMax(best + gcol, p);
    }
#undef STAGE
#undef COMPUTE
}

// =====================================================================
// Kernel 3: per-row fp32 loss term: log(||x_r - x_I + 1e-6|| + 1e-8)
// =====================================================================
__global__ void k_rowloss(const float* __restrict__ x,
                          const unsigned long long* __restrict__ best,
                          float* __restrict__ rowloss) {
    int wave = (int)threadIdx.x >> 6, lane = (int)threadIdx.x & 63;
    int r = (int)blockIdx.x * 4 + wave;
    unsigned long long p = best[r];
    int nb = (int)(0xFFFFFFFFu - (unsigned)(p & 0xFFFFFFFFull));
    const float4* xr = (const float4*)(x + (size_t)r  * DIM);
    const float4* xn = (const float4*)(x + (size_t)nb * DIM);
    float s = 0.f;
#pragma unroll
    for (int i = 0; i < 2; ++i) {
        float4 a = xr[lane * 2 + i];
        float4 b = xn[lane * 2 + i];
        float d0 = a.x - b.x + 1e-6f;
        float d1 = a.y - b.y + 1e-6f;
        float d2 = a.z - b.z + 1e-6f;
        float d3 = a.w - b.w + 1e-6f;
        s = fmaf(d0, d0, s); s = fmaf(d1, d1, s);
        s = fmaf(d2, d2, s); s = fmaf(d3, d3, s);
    }
#pragma unroll
    for (int m = 1; m < 64; m <<= 1) s += __shfl_xor(s, m, 64);
    if (lane == 0) rowloss[r] = logf(sqrtf(s) + 1e-8f);
}

// =====================================================================
// Kernel 4: deterministic single-block reduction -> scalar
// =====================================================================
__global__ void k_reduce(const float* __restrict__ rowloss, float* __restrict__ out) {
    __shared__ float sm[256];
    float s = 0.f;
    for (int i = (int)threadIdx.x; i < N_PTS; i += 256) s += rowloss[i];
    sm[threadIdx.x] = s;
    __syncthreads();
    for (int st = 128; st > 0; st >>= 1) {
        if ((int)threadIdx.x < st) sm[threadIdx.x] += sm[threadIdx.x + st];
        __syncthreads();
    }
    if (threadIdx.x == 0) out[0] = -0.1f * sm[0] / (float)N_PTS;
}

extern "C" void kernel_launch(void* const* d_in, const int* in_sizes, int n_in,
                              void* d_out, int out_size, void* d_ws, size_t ws_size,
                              hipStream_t stream) {
    const float* x = (const float*)d_in[0];
    float* out = (float*)d_out;
    char* ws = (char*)d_ws;

    // ws layout: [i8 X: 8 MB][best u64[N]: 128 KB][rowloss f32[N]: 64 KB]
    char* xq = ws;
    unsigned long long* best = (unsigned long long*)(ws + (size_t)N_PTS * DIM);
    float* rowloss = (float*)(ws + (size_t)N_PTS * DIM + (size_t)N_PTS * 8);

    k_quant<<<dim3(4096), dim3(256), 0, stream>>>(x, xq, best);
    k_gemm_argmax<<<dim3(NTRI), dim3(256), 0, stream>>>(xq, best);
    k_rowloss<<<dim3(N_PTS / 4), dim3(256), 0, stream>>>(x, best, rowloss);
    k_reduce<<<dim3(1), dim3(256), 0, stream>>>(rowloss, out);
}

// Round 5
// 235.413 us; speedup vs baseline: 1.5021x; 1.1122x over previous
//
#include <hip/hip_runtime.h>
#include <hip/hip_bf16.h>
#include <math.h>

#define N_PTS 16384
#define DIM   512
#define BM    128               // tile M = N
#define BK    64                // i8: 64-byte LDS rows
#define NBLK  (N_PTS / BM)      // 128
#define NTRI  (NBLK * (NBLK + 1) / 2)  // 8256
#define TILE_B (BM * BK)        // 8192 bytes per operand tile
#define QSCALE 23.0f

typedef int i32x4  __attribute__((ext_vector_type(4)));
typedef int i32x16 __attribute__((ext_vector_type(16)));
typedef unsigned long long u64;

#define VMC0    asm volatile("s_waitcnt vmcnt(0)" ::: "memory")
#define BARRIER do { __builtin_amdgcn_s_barrier(); } while (0)

__device__ __forceinline__ u64 pmax64(u64 a, u64 b) { return a > b ? a : b; }
// order-preserving i32 -> u32
__device__ __forceinline__ unsigned int iord(int v) { return (unsigned)v ^ 0x80000000u; }
__device__ __forceinline__ u64 packv(int v, int idx) {
    return ((u64)iord(v) << 32) | (unsigned)(0xFFFFFFFFu - (unsigned)idx);
}

// =====================================================================
// Kernel 1: fp32 -> int8 quantize (q = rint(23*x), |x|<5.5 -> no clip)
//           + init best[] = 0 (used by fallback path only; harmless in P-mode)
// =====================================================================
__global__ void k_quant(const float* __restrict__ x,
                        char* __restrict__ xq,
                        u64* __restrict__ best) {
    int t = blockIdx.x * blockDim.x + threadIdx.x;
    size_t e = (size_t)t * 8;
    float4 f0 = *(const float4*)(x + e);
    float4 f1 = *(const float4*)(x + e + 4);
    auto q8 = [](float v) -> int {
        return (int)rintf(fminf(fmaxf(v * QSCALE, -127.0f), 127.0f));
    };
    int lo = (q8(f0.x) & 255) | ((q8(f0.y) & 255) << 8)
           | ((q8(f0.z) & 255) << 16) | ((q8(f0.w) & 255) << 24);
    int hi = (q8(f1.x) & 255) | ((q8(f1.y) & 255) << 8)
           | ((q8(f1.z) & 255) << 16) | ((q8(f1.w) & 255) << 24);
    int2 o; o.x = lo; o.y = hi;
    *(int2*)(xq + e) = o;
    if (t < N_PTS) best[t] = 0ull;
}

// =====================================================================
// Kernel 2: S = Xq * Xq^T (int32 exact) on upper-tri 128x128 tiles,
// 4 waves (2x2, 64x64/wave), 32x32x32 i8 MFMA, BK=64, double-buffer
// 2-phase pipeline. LDS XOR-swizzle q ^= (row>>1)&3 (all 32 banks live),
// inverse-swizzled global source. Epilogue: per-tile row/col winners ->
// PT[slot][row] plain coalesced stores (USEP) or atomicMax (fallback).
// =====================================================================
template <bool USEP>
__global__ void k_gemm_argmax(const char* __restrict__ xq,
                              u64* __restrict__ PT,      // [NBLK][N_PTS]
                              u64* __restrict__ best) {
    __shared__ __align__(16) char As0[TILE_B], Bs0[TILE_B];
    __shared__ __align__(16) char As1[TILE_B], Bs1[TILE_B];

    // T1: XCD-aware bijective swizzle (8256 % 8 == 0)
    int t0i = (int)blockIdx.x;
    int t = (t0i & 7) * (NTRI / 8) + (t0i >> 3);

    // triangle decode: t = bn*(bn+1)/2 + bm, bm <= bn
    int bn = (int)((sqrtf(8.0f * (float)t + 1.0f) - 1.0f) * 0.5f);
    while ((bn + 1) * (bn + 2) / 2 <= t) ++bn;
    while (bn * (bn + 1) / 2 > t) --bn;
    int bm = t - bn * (bn + 1) / 2;

    const int tid  = (int)threadIdx.x;
    const int lane = tid & 63;
    const int wave = tid >> 6;       // 0..3
    const int wr   = wave >> 1;      // 0/1 -> 64-row band
    const int wc   = wave & 1;       // 0/1 -> 64-col band
    const int l31  = lane & 31;
    const int h    = lane >> 5;      // k-half of A/B frag; row-group of C

    const int arow0 = bm * BM;
    const int brow0 = bn * BM;

    // staging: 8KB tile = 512 x 16B chunks, thread covers chunks {tid, 256+tid}
    // chunk ci: row = ci>>2, p = ci&3. LDS linear; SOURCE inverse-swizzled:
    // col16 = p ^ ((row>>1)&3)
    const int srow   = tid >> 2;                        // set0 row; set1 = +64
    const int scol16 = (tid & 3) ^ ((tid >> 3) & 3);    // (row>>1)&3 == (tid>>3)&3
    const char* gA0 = xq + (size_t)(arow0 + srow)      * DIM + scol16 * 16;
    const char* gA1 = xq + (size_t)(arow0 + 64 + srow) * DIM + scol16 * 16;
    const char* gB0 = xq + (size_t)(brow0 + srow)      * DIM + scol16 * 16;
    const char* gB1 = xq + (size_t)(brow0 + 64 + srow) * DIM + scol16 * 16;
    const int cb0 = (tid & ~63) * 16;
    const int cb1 = (256 + (tid & ~63)) * 16;

#define STAGE(Adst, Bdst, kt)                                                        \
    do {                                                                             \
        int ko = (kt) * BK;                                                          \
        __builtin_amdgcn_global_load_lds(                                            \
            (const __attribute__((address_space(1))) void*)(gA0 + ko),               \
            (__attribute__((address_space(3))) void*)((Adst) + cb0), 16, 0, 0);      \
        __builtin_amdgcn_global_load_lds(                                            \
            (const __attribute__((address_space(1))) void*)(gA1 + ko),               \
            (__attribute__((address_space(3))) void*)((Adst) + cb1), 16, 0, 0);      \
        __builtin_amdgcn_global_load_lds(                                            \
            (const __attribute__((address_space(1))) void*)(gB0 + ko),               \
            (__attribute__((address_space(3))) void*)((Bdst) + cb0), 16, 0, 0);      \
        __builtin_amdgcn_global_load_lds(                                            \
            (const __attribute__((address_space(1))) void*)(gB1 + ko),               \
            (__attribute__((address_space(3))) void*)((Bdst) + cb1), 16, 0, 0);      \
    } while (0)

    // fragment read byte offsets: row*64 + ((q ^ ((row>>1)&3))<<4), q = s*2+h
    // row = band + m*32 + l31; (row>>1)&3 == (l31>>1)&3 (bands are mult of 8)
    const int rw = (l31 >> 1) & 3;
    int aoff[2], boff[2];
#pragma unroll
    for (int m = 0; m < 2; ++m)
        aoff[m] = (wr * 64 + m * 32 + l31) * 64 + ((h ^ rw) << 4);   // s=0; s=1: ^32
#pragma unroll
    for (int n = 0; n < 2; ++n)
        boff[n] = (wc * 64 + n * 32 + l31) * 64 + ((h ^ rw) << 4);

    i32x16 acc[2][2] = {};

#define COMPUTE(Asrc, Bsrc)                                                          \
    do {                                                                             \
        i32x4 a0 = *(const i32x4*)((Asrc) + aoff[0]);                                \
        i32x4 a1 = *(const i32x4*)((Asrc) + aoff[1]);                                \
        i32x4 b0 = *(const i32x4*)((Bsrc) + boff[0]);                                \
        i32x4 b1 = *(const i32x4*)((Bsrc) + boff[1]);                                \
        i32x4 a2 = *(const i32x4*)((Asrc) + (aoff[0] ^ 32));                         \
        i32x4 a3 = *(const i32x4*)((Asrc) + (aoff[1] ^ 32));                         \
        i32x4 b2 = *(const i32x4*)((Bsrc) + (boff[0] ^ 32));                         \
        i32x4 b3 = *(const i32x4*)((Bsrc) + (boff[1] ^ 32));                         \
        __builtin_amdgcn_s_setprio(1);                                               \
        acc[0][0] = __builtin_amdgcn_mfma_i32_32x32x32_i8(a0, b0, acc[0][0], 0, 0, 0); \
        acc[0][1] = __builtin_amdgcn_mfma_i32_32x32x32_i8(a0, b1, acc[0][1], 0, 0, 0); \
        acc[1][0] = __builtin_amdgcn_mfma_i32_32x32x32_i8(a1, b0, acc[1][0], 0, 0, 0); \
        acc[1][1] = __builtin_amdgcn_mfma_i32_32x32x32_i8(a1, b1, acc[1][1], 0, 0, 0); \
        acc[0][0] = __builtin_amdgcn_mfma_i32_32x32x32_i8(a2, b2, acc[0][0], 0, 0, 0); \
        acc[0][1] = __builtin_amdgcn_mfma_i32_32x32x32_i8(a2, b3, acc[0][1], 0, 0, 0); \
        acc[1][0] = __builtin_amdgcn_mfma_i32_32x32x32_i8(a3, b2, acc[1][0], 0, 0, 0); \
        acc[1][1] = __builtin_amdgcn_mfma_i32_32x32x32_i8(a3, b3, acc[1][1], 0, 0, 0); \
        __builtin_amdgcn_s_setprio(0);                                               \
    } while (0)

    // ---- prologue ----
    STAGE(As0, Bs0, 0);
    VMC0;
    BARRIER;

    // ---- main loop: 8 K-tiles of 64 ----
    for (int i = 0; i < 4; ++i) {
        STAGE(As1, Bs1, 2 * i + 1);
        COMPUTE(As0, Bs0);
        VMC0;
        BARRIER;
        if (i < 3) STAGE(As0, Bs0, 2 * i + 2);
        COMPUTE(As1, Bs1);
        if (i < 3) { VMC0; BARRIER; }
    }

    // ---- epilogue ----
    // C/D 32x32 layout: col = lane&31, row = (r&3) + 8*(r>>2) + 4*(lane>>5)
    if constexpr (USEP) {
        u64* rbuf = (u64*)As0;   // [128][2] row winners (As0 quiesced)
        u64* cbuf = (u64*)Bs0;   // [128][2] col winners

        // ROW view: winner over this wave's 64 cols, per row
#pragma unroll
        for (int m = 0; m < 2; ++m) {
#pragma unroll
            for (int r = 0; r < 16; ++r) {
                int rl = wr * 64 + m * 32 + (r & 3) + 8 * (r >> 2) + 4 * h;
                int grow = arow0 + rl;
                int gcol0 = brow0 + wc * 64 + l31;
                int gcol1 = gcol0 + 32;
                int v0 = (gcol0 == grow) ? (int)0x80000000 : acc[m][0][r];
                int v1 = (gcol1 == grow) ? (int)0x80000000 : acc[m][1][r];
                u64 p = pmax64(packv(v0, gcol0), packv(v1, gcol1));
                p = pmax64(p, __shfl_xor(p, 1, 64));
                p = pmax64(p, __shfl_xor(p, 2, 64));
                p = pmax64(p, __shfl_xor(p, 4, 64));
                p = pmax64(p, __shfl_xor(p, 8, 64));
                p = pmax64(p, __shfl_xor(p, 16, 64));
                if (l31 == 0) rbuf[rl * 2 + wc] = p;   // lanes 0 (h=0) & 32 (h=1)
            }
        }
        // COL view: winner over this wave's 64 rows, per col (register-local)
#pragma unroll
        for (int n = 0; n < 2; ++n) {
            int cl = wc * 64 + n * 32 + l31;
            int gcol = brow0 + cl;
            u64 p = 0ull;
#pragma unroll
            for (int m = 0; m < 2; ++m) {
#pragma unroll
                for (int r = 0; r < 16; ++r) {
                    int grow = arow0 + wr * 64 + m * 32 + (r & 3) + 8 * (r >> 2) + 4 * h;
                    int v = (grow == gcol) ? (int)0x80000000 : acc[m][n][r];
                    p = pmax64(p, packv(v, grow));
                }
            }
            p = pmax64(p, __shfl_xor(p, 32, 64));      // merge h-halves (same col)
            if (h == 0) cbuf[cl * 2 + wr] = p;
        }
        __syncthreads();
        // coalesced PT stores: slot bn <- rows of bm-block; slot bm <- rows of bn-block
        if (tid < 128) {
            u64 w = pmax64(rbuf[tid * 2], rbuf[tid * 2 + 1]);
            PT[(size_t)bn * N_PTS + arow0 + tid] = w;
        } else if (bm != bn) {                          // diagonal: col view redundant
            int c = tid & 127;
            u64 w = pmax64(cbuf[c * 2], cbuf[c * 2 + 1]);
            PT[(size_t)bm * N_PTS + brow0 + c] = w;
        }
    } else {
        // fallback: atomic path (R4)
#pragma unroll
        for (int m = 0; m < 2; ++m) {
#pragma unroll
            for (int r = 0; r < 16; ++r) {
                int grow = arow0 + wr * 64 + m * 32 + (r & 3) + 8 * (r >> 2) + 4 * h;
                int gcol0 = brow0 + wc * 64 + l31;
                int gcol1 = gcol0 + 32;
                int v0 = (gcol0 == grow) ? (int)0x80000000 : acc[m][0][r];
                int v1 = (gcol1 == grow) ? (int)0x80000000 : acc[m][1][r];
                u64 p = pmax64(packv(v0, gcol0), packv(v1, gcol1));
                p = pmax64(p, __shfl_xor(p, 1, 64));
                p = pmax64(p, __shfl_xor(p, 2, 64));
                p = pmax64(p, __shfl_xor(p, 4, 64));
                p = pmax64(p, __shfl_xor(p, 8, 64));
                p = pmax64(p, __shfl_xor(p, 16, 64));
                if (l31 == 0) atomicMax(best + grow, p);
            }
        }
#pragma unroll
        for (int n = 0; n < 2; ++n) {
            int gcol = brow0 + wc * 64 + n * 32 + l31;
            u64 p = 0ull;
#pragma unroll
            for (int m = 0; m < 2; ++m) {
#pragma unroll
                for (int r = 0; r < 16; ++r) {
                    int grow = arow0 + wr * 64 + m * 32 + (r & 3) + 8 * (r >> 2) + 4 * h;
                    int v = (grow == gcol) ? (int)0x80000000 : acc[m][n][r];
                    p = pmax64(p, packv(v, grow));
                }
            }
            p = pmax64(p, __shfl_xor(p, 32, 64));
            if (h == 0 && bm != bn) atomicMax(best + gcol, p);
        }
    }
#undef STAGE
#undef COMPUTE
}

// =====================================================================
// Kernel 3a (P-mode): reduce PT columns -> nb[row]; coalesced across threads
// =====================================================================
__global__ void k_reduceP(const u64* __restrict__ PT, int* __restrict__ nb) {
    int r = (int)blockIdx.x * 256 + (int)threadIdx.x;
    u64 p0 = PT[r], p1 = PT[(size_t)N_PTS + r];
    u64 p2 = PT[(size_t)2 * N_PTS + r], p3 = PT[(size_t)3 * N_PTS + r];
    for (int s = 4; s < NBLK; s += 4) {
        p0 = pmax64(p0, PT[(size_t)s * N_PTS + r]);
        p1 = pmax64(p1, PT[(size_t)(s + 1) * N_PTS + r]);
        p2 = pmax64(p2, PT[(size_t)(s + 2) * N_PTS + r]);
        p3 = pmax64(p3, PT[(size_t)(s + 3) * N_PTS + r]);
    }
    u64 p = pmax64(pmax64(p0, p1), pmax64(p2, p3));
    nb[r] = (int)(0xFFFFFFFFu - (unsigned)(p & 0xFFFFFFFFull));
}

// Kernel 3b (fallback): decode best -> nb
__global__ void k_best2nb(const u64* __restrict__ best, int* __restrict__ nb) {
    int r = (int)blockIdx.x * 256 + (int)threadIdx.x;
    nb[r] = (int)(0xFFFFFFFFu - (unsigned)(best[r] & 0xFFFFFFFFull));
}

// =====================================================================
// Kernel 4: per-row fp32 loss term: log(||x_r - x_I + 1e-6|| + 1e-8)
// =====================================================================
__global__ void k_rowloss(const float* __restrict__ x,
                          const int* __restrict__ nb,
                          float* __restrict__ rowloss) {
    int wave = (int)threadIdx.x >> 6, lane = (int)threadIdx.x & 63;
    int r = (int)blockIdx.x * 4 + wave;
    int nbi = nb[r];
    const float4* xr = (const float4*)(x + (size_t)r   * DIM);
    const float4* xn = (const float4*)(x + (size_t)nbi * DIM);
    float s = 0.f;
#pragma unroll
    for (int i = 0; i < 2; ++i) {
        float4 a = xr[lane * 2 + i];
        float4 b = xn[lane * 2 + i];
        float d0 = a.x - b.x + 1e-6f;
        float d1 = a.y - b.y + 1e-6f;
        float d2 = a.z - b.z + 1e-6f;
        float d3 = a.w - b.w + 1e-6f;
        s = fmaf(d0, d0, s); s = fmaf(d1, d1, s);
        s = fmaf(d2, d2, s); s = fmaf(d3, d3, s);
    }
#pragma unroll
    for (int m = 1; m < 64; m <<= 1) s += __shfl_xor(s, m, 64);
    if (lane == 0) rowloss[r] = logf(sqrtf(s) + 1e-8f);
}

// =====================================================================
// Kernel 5: deterministic single-block reduction -> scalar
// =====================================================================
__global__ void k_reduce(const float* __restrict__ rowloss, float* __restrict__ out) {
    __shared__ float sm[256];
    float s = 0.f;
    for (int i = (int)threadIdx.x; i < N_PTS; i += 256) s += rowloss[i];
    sm[threadIdx.x] = s;
    __syncthreads();
    for (int st = 128; st > 0; st >>= 1) {
        if ((int)threadIdx.x < st) sm[threadIdx.x] += sm[threadIdx.x + st];
        __syncthreads();
    }
    if (threadIdx.x == 0) out[0] = -0.1f * sm[0] / (float)N_PTS;
}

extern "C" void kernel_launch(void* const* d_in, const int* in_sizes, int n_in,
                              void* d_out, int out_size, void* d_ws, size_t ws_size,
                              hipStream_t stream) {
    const float* x = (const float*)d_in[0];
    float* out = (float*)d_out;
    char* ws = (char*)d_ws;

    // P-mode layout: [xq 8MB][PT 16MB][nb 64KB][rowloss 64KB]
    // fallback:      [xq 8MB][best 128KB][nb 64KB][rowloss 64KB]
    const size_t xqB = (size_t)N_PTS * DIM;                 // 8 MB
    const size_t ptB = (size_t)NBLK * N_PTS * 8;            // 16 MB
    char* xq = ws;
    u64*  PT = (u64*)(ws + xqB);
    u64*  best = (u64*)(ws + xqB);                          // aliases PT (ok by phase)
    const bool useP = ws_size >= xqB + ptB + 2 * (size_t)N_PTS * 8;

    int*   nb;
    float* rowloss;
    if (useP) {
        nb = (int*)(ws + xqB + ptB);
        rowloss = (float*)(ws + xqB + ptB + (size_t)N_PTS * 4);
    } else {
        nb = (int*)(ws + xqB + (size_t)N_PTS * 8);
        rowloss = (float*)(ws + xqB + (size_t)N_PTS * 8 + (size_t)N_PTS * 4);
    }

    k_quant<<<dim3(4096), dim3(256), 0, stream>>>(x, xq, best);
    if (useP) {
        k_gemm_argmax<true><<<dim3(NTRI), dim3(256), 0, stream>>>(xq, PT, best);
        k_reduceP<<<dim3(N_PTS / 256), dim3(256), 0, stream>>>(PT, nb);
    } else {
        k_gemm_argmax<false><<<dim3(NTRI), dim3(256), 0, stream>>>(xq, PT, best);
        k_best2nb<<<dim3(N_PTS / 256), dim3(256), 0, stream>>>(best, nb);
    }
    k_rowloss<<<dim3(N_PTS / 4), dim3(256), 0, stream>>>(x, nb, rowloss);
    k_reduce<<<dim3(1), dim3(256), 0, stream>>>(rowloss, out);
}

// Round 6
// 194.620 us; speedup vs baseline: 1.8169x; 1.2096x over previous
//
#include <hip/hip_runtime.h>
#include <hip/hip_bf16.h>
#include <math.h>

#define N_PTS 16384
#define DIM   512
#define BM    128               // tile M = N
#define BK    64                // i8: 64-byte LDS rows
#define NBLK  (N_PTS / BM)      // 128
#define NTRI  (NBLK * (NBLK + 1) / 2)  // 8256
#define TILE_B (BM * BK)        // 8192 bytes per operand tile
#define QSCALE 23.0f
#define BIAS   (1 << 23)        // |dot| <= 512*127*127 = 8258048 < 2^23... (<2^24); u=dot+BIAS < 2^25

typedef int i32x4  __attribute__((ext_vector_type(4)));
typedef int i32x16 __attribute__((ext_vector_type(16)));
typedef unsigned long long u64;

#define VMC0    asm volatile("s_waitcnt vmcnt(0)" ::: "memory")
#define BARRIER do { __builtin_amdgcn_s_barrier(); } while (0)

__device__ __forceinline__ u64 pmax64(u64 a, u64 b) { return a > b ? a : b; }
__device__ __forceinline__ unsigned umax32(unsigned a, unsigned b) { return a > b ? a : b; }
__device__ __forceinline__ unsigned int iord(int v) { return (unsigned)v ^ 0x80000000u; }
__device__ __forceinline__ u64 packv(int v, int idx) {
    return ((u64)iord(v) << 32) | (unsigned)(0xFFFFFFFFu - (unsigned)idx);
}

// =====================================================================
// Kernel 1: fp32 -> int8 quantize (q = rint(23*x), |x|<5.5 -> no clip)
// =====================================================================
__global__ void k_quant(const float* __restrict__ x,
                        char* __restrict__ xq,
                        u64* __restrict__ best) {
    int t = blockIdx.x * blockDim.x + threadIdx.x;
    size_t e = (size_t)t * 8;
    float4 f0 = *(const float4*)(x + e);
    float4 f1 = *(const float4*)(x + e + 4);
    auto q8 = [](float v) -> int {
        return (int)rintf(fminf(fmaxf(v * QSCALE, -127.0f), 127.0f));
    };
    int lo = (q8(f0.x) & 255) | ((q8(f0.y) & 255) << 8)
           | ((q8(f0.z) & 255) << 16) | ((q8(f0.w) & 255) << 24);
    int hi = (q8(f1.x) & 255) | ((q8(f1.y) & 255) << 8)
           | ((q8(f1.z) & 255) << 16) | ((q8(f1.w) & 255) << 24);
    int2 o; o.x = lo; o.y = hi;
    *(int2*)(xq + e) = o;
    if (t < N_PTS) best[t] = 0ull;   // fallback path only
}

// =====================================================================
// Kernel 2: S = Xq * Xq^T (int32 exact) on upper-tri 128x128 tiles,
// 4 waves (2x2, 64x64/wave), 32x32x32 i8 MFMA, BK=64, double-buffer
// 2-phase pipeline, XOR-swizzled LDS (q ^= (row>>1)&3, inverse-swz src).
// Epilogue: u32-packed winners ((dot+2^23)<<7 | (127-rel)) ->
// PT[slot][row] coalesced u32 stores (USEP) or u64 atomicMax (fallback).
// =====================================================================
template <bool USEP>
__global__ void k_gemm_argmax(const char* __restrict__ xq,
                              unsigned* __restrict__ PT,   // [NBLK][N_PTS] u32
                              u64* __restrict__ best) {
    __shared__ __align__(16) char As0[TILE_B], Bs0[TILE_B];
    __shared__ __align__(16) char As1[TILE_B], Bs1[TILE_B];

    // T1: XCD-aware bijective swizzle (8256 % 8 == 0)
    int t0i = (int)blockIdx.x;
    int t = (t0i & 7) * (NTRI / 8) + (t0i >> 3);

    // triangle decode: t = bn*(bn+1)/2 + bm, bm <= bn
    int bn = (int)((sqrtf(8.0f * (float)t + 1.0f) - 1.0f) * 0.5f);
    while ((bn + 1) * (bn + 2) / 2 <= t) ++bn;
    while (bn * (bn + 1) / 2 > t) --bn;
    int bm = t - bn * (bn + 1) / 2;

    const int tid  = (int)threadIdx.x;
    const int lane = tid & 63;
    const int wave = tid >> 6;       // 0..3
    const int wr   = wave >> 1;      // 0/1 -> 64-row band
    const int wc   = wave & 1;       // 0/1 -> 64-col band
    const int l31  = lane & 31;
    const int h    = lane >> 5;      // k-half of A/B frag; row-group of C

    const int arow0 = bm * BM;
    const int brow0 = bn * BM;

    // staging: 8KB tile = 512 x 16B chunks, thread covers chunks {tid, 256+tid}
    // LDS linear; SOURCE inverse-swizzled: col16 = p ^ ((row>>1)&3)
    const int srow   = tid >> 2;
    const int scol16 = (tid & 3) ^ ((tid >> 3) & 3);
    const char* gA0 = xq + (size_t)(arow0 + srow)      * DIM + scol16 * 16;
    const char* gA1 = xq + (size_t)(arow0 + 64 + srow) * DIM + scol16 * 16;
    const char* gB0 = xq + (size_t)(brow0 + srow)      * DIM + scol16 * 16;
    const char* gB1 = xq + (size_t)(brow0 + 64 + srow) * DIM + scol16 * 16;
    const int cb0 = (tid & ~63) * 16;
    const int cb1 = (256 + (tid & ~63)) * 16;

#define STAGE(Adst, Bdst, kt)                                                        \
    do {                                                                             \
        int ko = (kt) * BK;                                                          \
        __builtin_amdgcn_global_load_lds(                                            \
            (const __attribute__((address_space(1))) void*)(gA0 + ko),               \
            (__attribute__((address_space(3))) void*)((Adst) + cb0), 16, 0, 0);      \
        __builtin_amdgcn_global_load_lds(                                            \
            (const __attribute__((address_space(1))) void*)(gA1 + ko),               \
            (__attribute__((address_space(3))) void*)((Adst) + cb1), 16, 0, 0);      \
        __builtin_amdgcn_global_load_lds(                                            \
            (const __attribute__((address_space(1))) void*)(gB0 + ko),               \
            (__attribute__((address_space(3))) void*)((Bdst) + cb0), 16, 0, 0);      \
        __builtin_amdgcn_global_load_lds(                                            \
            (const __attribute__((address_space(1))) void*)(gB1 + ko),               \
            (__attribute__((address_space(3))) void*)((Bdst) + cb1), 16, 0, 0);      \
    } while (0)

    // fragment read byte offsets: row*64 + ((q ^ ((row>>1)&3))<<4), q = s*2+h
    const int rw = (l31 >> 1) & 3;
    int aoff[2], boff[2];
#pragma unroll
    for (int m = 0; m < 2; ++m)
        aoff[m] = (wr * 64 + m * 32 + l31) * 64 + ((h ^ rw) << 4);   // s=0; s=1: ^32
#pragma unroll
    for (int n = 0; n < 2; ++n)
        boff[n] = (wc * 64 + n * 32 + l31) * 64 + ((h ^ rw) << 4);

    i32x16 acc[2][2] = {};

#define COMPUTE(Asrc, Bsrc)                                                          \
    do {                                                                             \
        i32x4 a0 = *(const i32x4*)((Asrc) + aoff[0]);                                \
        i32x4 a1 = *(const i32x4*)((Asrc) + aoff[1]);                                \
        i32x4 b0 = *(const i32x4*)((Bsrc) + boff[0]);                                \
        i32x4 b1 = *(const i32x4*)((Bsrc) + boff[1]);                                \
        i32x4 a2 = *(const i32x4*)((Asrc) + (aoff[0] ^ 32));                         \
        i32x4 a3 = *(const i32x4*)((Asrc) + (aoff[1] ^ 32));                         \
        i32x4 b2 = *(const i32x4*)((Bsrc) + (boff[0] ^ 32));                         \
        i32x4 b3 = *(const i32x4*)((Bsrc) + (boff[1] ^ 32));                         \
        acc[0][0] = __builtin_amdgcn_mfma_i32_32x32x32_i8(a0, b0, acc[0][0], 0, 0, 0); \
        acc[0][1] = __builtin_amdgcn_mfma_i32_32x32x32_i8(a0, b1, acc[0][1], 0, 0, 0); \
        acc[1][0] = __builtin_amdgcn_mfma_i32_32x32x32_i8(a1, b0, acc[1][0], 0, 0, 0); \
        acc[1][1] = __builtin_amdgcn_mfma_i32_32x32x32_i8(a1, b1, acc[1][1], 0, 0, 0); \
        acc[0][0] = __builtin_amdgcn_mfma_i32_32x32x32_i8(a2, b2, acc[0][0], 0, 0, 0); \
        acc[0][1] = __builtin_amdgcn_mfma_i32_32x32x32_i8(a2, b3, acc[0][1], 0, 0, 0); \
        acc[1][0] = __builtin_amdgcn_mfma_i32_32x32x32_i8(a3, b2, acc[1][0], 0, 0, 0); \
        acc[1][1] = __builtin_amdgcn_mfma_i32_32x32x32_i8(a3, b3, acc[1][1], 0, 0, 0); \
    } while (0)

    // ---- prologue ----
    STAGE(As0, Bs0, 0);
    VMC0;
    BARRIER;

    // ---- main loop: 8 K-tiles of 64 ----
    for (int i = 0; i < 4; ++i) {
        STAGE(As1, Bs1, 2 * i + 1);
        COMPUTE(As0, Bs0);
        VMC0;
        BARRIER;
        if (i < 3) STAGE(As0, Bs0, 2 * i + 2);
        COMPUTE(As1, Bs1);
        if (i < 3) { VMC0; BARRIER; }
    }

    // ---- epilogue ----
    // C/D 32x32 layout: col = lane&31, row = (r&3) + 8*(r>>2) + 4*(lane>>5)
    if constexpr (USEP) {
        unsigned* rbuf = (unsigned*)As0;   // [128][2] row winners (As0 quiesced)
        unsigned* cbuf = (unsigned*)Bs0;   // [128][2] col winners

        const int relc0 = wc * 64 + l31;   // this lane's col (n=0) rel index
        const unsigned idx0 = 127 - relc0;
        const unsigned idx1 = idx0 - 32;
        const int h4 = h * 4;

        auto epilogue = [&](bool diag) __attribute__((always_inline)) {
            // ROW view: winner over this wave's 64 cols, per row
#pragma unroll
            for (int m = 0; m < 2; ++m) {
#pragma unroll
                for (int r = 0; r < 16; ++r) {
                    int rl = wr * 64 + m * 32 + (r & 3) + 8 * (r >> 2) + h4;
                    unsigned p0 = ((unsigned)(acc[m][0][r] + BIAS) << 7) | idx0;
                    unsigned p1 = ((unsigned)(acc[m][1][r] + BIAS) << 7) | idx1;
                    if (diag && relc0 == rl) p0 = 0;
                    if (diag && relc0 + 32 == rl) p1 = 0;
                    unsigned p = umax32(p0, p1);
                    p = umax32(p, (unsigned)__shfl_xor((int)p, 1, 64));
                    p = umax32(p, (unsigned)__shfl_xor((int)p, 2, 64));
                    p = umax32(p, (unsigned)__shfl_xor((int)p, 4, 64));
                    p = umax32(p, (unsigned)__shfl_xor((int)p, 8, 64));
                    p = umax32(p, (unsigned)__shfl_xor((int)p, 16, 64));
                    if (l31 == 0) rbuf[rl * 2 + wc] = p;
                }
            }
            // COL view: winner over this wave's 64 rows, per col.
            // idx bits use compile-time base (127-base); correct by -4h after.
#pragma unroll
            for (int n = 0; n < 2; ++n) {
                int cl = wc * 64 + n * 32 + l31;
                unsigned bst = 0;
#pragma unroll
                for (int m = 0; m < 2; ++m) {
#pragma unroll
                    for (int r = 0; r < 16; ++r) {
                        int base = wr * 64 + m * 32 + (r & 3) + 8 * (r >> 2); // + h4 = true rel
                        unsigned q = ((unsigned)(acc[m][n][r] + BIAS) << 7)
                                   | (unsigned)(127 - base);
                        if (diag && base + h4 == cl) q = 0;
                        bst = umax32(bst, q);
                    }
                }
                bst -= (unsigned)h4;   // apply true rel (all candidates share h)
                bst = umax32(bst, (unsigned)__shfl_xor((int)bst, 32, 64));
                if (h == 0) cbuf[cl * 2 + wr] = bst;
            }
        };
        if (bm == bn) epilogue(true); else epilogue(false);

        __syncthreads();
        // coalesced PT stores: slot bn <- rows of bm-block; slot bm <- rows of bn-block
        if (tid < 128) {
            unsigned w = umax32(rbuf[tid * 2], rbuf[tid * 2 + 1]);
            PT[(size_t)bn * N_PTS + arow0 + tid] = w;
        } else if (bm != bn) {
            int c = tid & 127;
            unsigned w = umax32(cbuf[c * 2], cbuf[c * 2 + 1]);
            PT[(size_t)bm * N_PTS + brow0 + c] = w;
        }
    } else {
        // fallback: u64 atomic path
#pragma unroll
        for (int m = 0; m < 2; ++m) {
#pragma unroll
            for (int r = 0; r < 16; ++r) {
                int grow = arow0 + wr * 64 + m * 32 + (r & 3) + 8 * (r >> 2) + 4 * h;
                int gcol0 = brow0 + wc * 64 + l31;
                int gcol1 = gcol0 + 32;
                int v0 = (gcol0 == grow) ? (int)0x80000000 : acc[m][0][r];
                int v1 = (gcol1 == grow) ? (int)0x80000000 : acc[m][1][r];
                u64 p = pmax64(packv(v0, gcol0), packv(v1, gcol1));
                p = pmax64(p, __shfl_xor(p, 1, 64));
                p = pmax64(p, __shfl_xor(p, 2, 64));
                p = pmax64(p, __shfl_xor(p, 4, 64));
                p = pmax64(p, __shfl_xor(p, 8, 64));
                p = pmax64(p, __shfl_xor(p, 16, 64));
                if (l31 == 0) atomicMax(best + grow, p);
            }
        }
#pragma unroll
        for (int n = 0; n < 2; ++n) {
            int gcol = brow0 + wc * 64 + n * 32 + l31;
            u64 p = 0ull;
#pragma unroll
            for (int m = 0; m < 2; ++m) {
#pragma unroll
                for (int r = 0; r < 16; ++r) {
                    int grow = arow0 + wr * 64 + m * 32 + (r & 3) + 8 * (r >> 2) + 4 * h;
                    int v = (grow == gcol) ? (int)0x80000000 : acc[m][n][r];
                    p = pmax64(p, packv(v, grow));
                }
            }
            p = pmax64(p, __shfl_xor(p, 32, 64));
            if (h == 0 && bm != bn) atomicMax(best + gcol, p);
        }
    }
#undef STAGE
#undef COMPUTE
}

// =====================================================================
// Kernel 3a (P-mode): reduce PT columns -> nb[row].
// Tie rule: smallest global index == (value, ~slot, ~rel) lexicographic max.
// =====================================================================
__global__ void k_reduceP(const unsigned* __restrict__ PT, int* __restrict__ nb) {
    int r = (int)blockIdx.x * 256 + (int)threadIdx.x;
    u64 bst = 0;
#pragma unroll 4
    for (int s = 0; s < NBLK; ++s) {
        unsigned p = PT[(size_t)s * N_PTS + r];
        u64 q = ((u64)(p >> 7) << 14) | ((u64)(127 - s) << 7) | (p & 127);
        bst = pmax64(bst, q);
    }
    int slot = 127 - (int)((bst >> 7) & 127);
    int rel  = 127 - (int)(bst & 127);
    nb[r] = slot * 128 + rel;
}

// Kernel 3b (fallback): decode best -> nb
__global__ void k_best2nb(const u64* __restrict__ best, int* __restrict__ nb) {
    int r = (int)blockIdx.x * 256 + (int)threadIdx.x;
    nb[r] = (int)(0xFFFFFFFFu - (unsigned)(best[r] & 0xFFFFFFFFull));
}

// =====================================================================
// Kernel 4: per-row fp32 loss term: log(||x_r - x_I + 1e-6|| + 1e-8)
// =====================================================================
__global__ void k_rowloss(const float* __restrict__ x,
                          const int* __restrict__ nb,
                          float* __restrict__ rowloss) {
    int wave = (int)threadIdx.x >> 6, lane = (int)threadIdx.x & 63;
    int r = (int)blockIdx.x * 4 + wave;
    int nbi = nb[r];
    const float4* xr = (const float4*)(x + (size_t)r   * DIM);
    const float4* xn = (const float4*)(x + (size_t)nbi * DIM);
    float s = 0.f;
#pragma unroll
    for (int i = 0; i < 2; ++i) {
        float4 a = xr[lane * 2 + i];
        float4 b = xn[lane * 2 + i];
        float d0 = a.x - b.x + 1e-6f;
        float d1 = a.y - b.y + 1e-6f;
        float d2 = a.z - b.z + 1e-6f;
        float d3 = a.w - b.w + 1e-6f;
        s = fmaf(d0, d0, s); s = fmaf(d1, d1, s);
        s = fmaf(d2, d2, s); s = fmaf(d3, d3, s);
    }
#pragma unroll
    for (int m = 1; m < 64; m <<= 1) s += __shfl_xor(s, m, 64);
    if (lane == 0) rowloss[r] = logf(sqrtf(s) + 1e-8f);
}

// =====================================================================
// Kernel 5: deterministic single-block reduction -> scalar
// =====================================================================
__global__ void k_reduce(const float* __restrict__ rowloss, float* __restrict__ out) {
    __shared__ float sm[256];
    float s = 0.f;
    for (int i = (int)threadIdx.x; i < N_PTS; i += 256) s += rowloss[i];
    sm[threadIdx.x] = s;
    __syncthreads();
    for (int st = 128; st > 0; st >>= 1) {
        if ((int)threadIdx.x < st) sm[threadIdx.x] += sm[threadIdx.x + st];
        __syncthreads();
    }
    if (threadIdx.x == 0) out[0] = -0.1f * sm[0] / (float)N_PTS;
}

extern "C" void kernel_launch(void* const* d_in, const int* in_sizes, int n_in,
                              void* d_out, int out_size, void* d_ws, size_t ws_size,
                              hipStream_t stream) {
    const float* x = (const float*)d_in[0];
    float* out = (float*)d_out;
    char* ws = (char*)d_ws;

    // P-mode layout: [xq 8MB][PT 8MB u32][nb 64KB][rowloss 64KB]
    // fallback:      [xq 8MB][best 128KB][nb 64KB][rowloss 64KB]
    const size_t xqB = (size_t)N_PTS * DIM;                 // 8 MB
    const size_t ptB = (size_t)NBLK * N_PTS * 4;            // 8 MB
    char* xq = ws;
    unsigned* PT = (unsigned*)(ws + xqB);
    u64* best = (u64*)(ws + xqB);                           // aliases PT (by phase)
    const bool useP = ws_size >= xqB + ptB + 2 * (size_t)N_PTS * 8;

    int*   nb;
    float* rowloss;
    if (useP) {
        nb = (int*)(ws + xqB + ptB);
        rowloss = (float*)(ws + xqB + ptB + (size_t)N_PTS * 4);
    } else {
        nb = (int*)(ws + xqB + (size_t)N_PTS * 8);
        rowloss = (float*)(ws + xqB + (size_t)N_PTS * 8 + (size_t)N_PTS * 4);
    }

    k_quant<<<dim3(4096), dim3(256), 0, stream>>>(x, xq, best);
    if (useP) {
        k_gemm_argmax<true><<<dim3(NTRI), dim3(256), 0, stream>>>(xq, PT, best);
        k_reduceP<<<dim3(N_PTS / 256), dim3(256), 0, stream>>>(PT, nb);
    } else {
        k_gemm_argmax<false><<<dim3(NTRI), dim3(256), 0, stream>>>(xq, PT, best);
        k_best2nb<<<dim3(N_PTS / 256), dim3(256), 0, stream>>>(best, nb);
    }
    k_rowloss<<<dim3(N_PTS / 4), dim3(256), 0, stream>>>(x, nb, rowloss);
    k_reduce<<<dim3(1), dim3(256), 0, stream>>>(rowloss, out);
}

// Round 8
// 183.029 us; speedup vs baseline: 1.9320x; 1.0633x over previous
//
#include <hip/hip_runtime.h>
#include <hip/hip_bf16.h>
#include <math.h>

#define N_PTS 16384
#define DIM   512
#define BMR   128               // tile rows
#define BNC   256               // tile cols
#define BK    64                // i8: 64-byte LDS rows
#define NRB   (N_PTS / BMR)     // 128 row-blocks
#define NCB   (N_PTS / BNC)     // 64 col-blocks
#define NTILE 4160              // sum_{g=0}^{63} 2*(64-g)
#define QSCALE 23.0f
#define BIAS   (1 << 23)        // |dot| <= 512*127^2 = 8258048 < 2^23

typedef int i32x4  __attribute__((ext_vector_type(4)));
typedef int i32x16 __attribute__((ext_vector_type(16)));
typedef unsigned long long u64;

#define VMC0    asm volatile("s_waitcnt vmcnt(0)" ::: "memory")
#define BARRIER __builtin_amdgcn_s_barrier()

__device__ __forceinline__ u64 pmax64(u64 a, u64 b) { return a > b ? a : b; }
__device__ __forceinline__ unsigned umax32(unsigned a, unsigned b) { return a > b ? a : b; }
// DPP-based max step (VALU, stays off the LDS crossbar). CTRL must be literal.
template <int CTRL>
__device__ __forceinline__ unsigned dppmax(unsigned p) {
    int t = __builtin_amdgcn_update_dpp(0, (int)p, CTRL, 0xF, 0xF, true);
    return umax32(p, (unsigned)t);
}
__device__ __forceinline__ void gll(const char* g, char* l) {
    __builtin_amdgcn_global_load_lds(
        (const __attribute__((address_space(1))) void*)g,
        (__attribute__((address_space(3))) void*)l, 16, 0, 0);
}

// =====================================================================
// Kernel 1: fp32 -> int8 quantize (q = rint(23*x), |x|<5.5 -> no clip)
// =====================================================================
__global__ void k_quant(const float* __restrict__ x, char* __restrict__ xq) {
    int t = blockIdx.x * blockDim.x + threadIdx.x;
    size_t e = (size_t)t * 8;
    float4 f0 = *(const float4*)(x + e);
    float4 f1 = *(const float4*)(x + e + 4);
    auto q8 = [](float v) -> int {
        return (int)rintf(fminf(fmaxf(v * QSCALE, -127.0f), 127.0f));
    };
    int lo = (q8(f0.x) & 255) | ((q8(f0.y) & 255) << 8)
           | ((q8(f0.z) & 255) << 16) | ((q8(f0.w) & 255) << 24);
    int hi = (q8(f1.x) & 255) | ((q8(f1.y) & 255) << 8)
           | ((q8(f1.z) & 255) << 16) | ((q8(f1.w) & 255) << 24);
    int2 o; o.x = lo; o.y = hi;
    *(int2*)(xq + e) = o;
}

// =====================================================================
// Kernel 2: 128x256 tiles (bc >= br>>1 covers all pairs; below-diagonal
// overlap cells are symmetric duplicates, harmless for max), 4 waves in
// 2x2 grid, wave tile 64x128 (acc 2x4 of 32x32), i8 MFMA, BK=64,
// double-buffered 2-phase pipeline, XOR-swizzled LDS. Epilogue:
// DPP-reduced row winners + in-register col winners -> PT slots.
// =====================================================================
__global__ __launch_bounds__(256, 2)
void k_gemm_argmax(const char* __restrict__ xq, unsigned* __restrict__ PT) {
    __shared__ __align__(16) char As0[BMR * BK], As1[BMR * BK];   // 8 KB each
    __shared__ __align__(16) char Bs0[BNC * BK], Bs1[BNC * BK];   // 16 KB each

    // T1: XCD swizzle (4160 % 8 == 0)
    int t0i = (int)blockIdx.x;
    int t = (t0i & 7) * (NTILE / 8) + (t0i >> 3);

    // decode t -> (br, bc): groups g = br>>1, S(g) = g*(129-g)
    int g = (int)((129.0f - sqrtf(16641.0f - 4.0f * (float)t)) * 0.5f);
    while (g * (129 - g) > t) --g;
    while ((g + 1) * (128 - g) <= t) ++g;
    int u = t - g * (129 - g);
    int bc = g + (u >> 1);
    int br = 2 * g + (u & 1);

    const int tid  = (int)threadIdx.x;
    const int lane = tid & 63;
    const int wave = tid >> 6;       // 0..3
    const int wr   = wave >> 1;      // 0/1 -> 64-row band
    const int wc   = wave & 1;       // 0/1 -> 128-col band
    const int l31  = lane & 31;
    const int h    = lane >> 5;

    const int arow0 = br * BMR;
    const int bcol0 = bc * BNC;

    // staging: A = 512 chunks (2/thread), B = 1024 chunks (4/thread)
    // LDS linear; SOURCE inverse-swizzled: col16 = (t&3) ^ ((row>>1)&3)
    const int srow   = tid >> 2;
    const int scol16 = (tid & 3) ^ ((tid >> 3) & 3);
    const char* gA0 = xq + (size_t)(arow0 + srow)       * DIM + scol16 * 16;
    const char* gA1 = xq + (size_t)(arow0 + 64 + srow)  * DIM + scol16 * 16;
    const char* gB0 = xq + (size_t)(bcol0 + srow)       * DIM + scol16 * 16;
    const char* gB1 = xq + (size_t)(bcol0 + 64 + srow)  * DIM + scol16 * 16;
    const char* gB2 = xq + (size_t)(bcol0 + 128 + srow) * DIM + scol16 * 16;
    const char* gB3 = xq + (size_t)(bcol0 + 192 + srow) * DIM + scol16 * 16;
    const int cbA0 = (tid & ~63) * 16;
    const int cbA1 = (256 + (tid & ~63)) * 16;
    const int cbB0 = cbA0, cbB1 = cbA1;
    const int cbB2 = (512 + (tid & ~63)) * 16;
    const int cbB3 = (768 + (tid & ~63)) * 16;

#define STAGE(Ad, Bd, kt)                                                \
    do {                                                                 \
        int ko = (kt) * BK;                                              \
        gll(gA0 + ko, (Ad) + cbA0); gll(gA1 + ko, (Ad) + cbA1);          \
        gll(gB0 + ko, (Bd) + cbB0); gll(gB1 + ko, (Bd) + cbB1);          \
        gll(gB2 + ko, (Bd) + cbB2); gll(gB3 + ko, (Bd) + cbB3);          \
    } while (0)

    // fragment read byte offsets: row*64 + ((q ^ ((row>>1)&3))<<4), q=s*2+h
    const int rw = (l31 >> 1) & 3;
    const int aoff0 = (wr * 64 + 0  + l31) * 64 + ((h ^ rw) << 4);
    const int aoff1 = (wr * 64 + 32 + l31) * 64 + ((h ^ rw) << 4);
    const int boff0 = (wc * 128 + 0   + l31) * 64 + ((h ^ rw) << 4);
    const int boff1 = (wc * 128 + 32  + l31) * 64 + ((h ^ rw) << 4);
    const int boff2 = (wc * 128 + 64  + l31) * 64 + ((h ^ rw) << 4);
    const int boff3 = (wc * 128 + 96  + l31) * 64 + ((h ^ rw) << 4);

    i32x16 acc[2][4] = {};

#define COMPUTE(As_, Bs_)                                                              \
    do {                                                                               \
        _Pragma("unroll")                                                              \
        for (int s = 0; s < 2; ++s) {                                                  \
            const int xo = s * 32;                                                     \
            i32x4 a0 = *(const i32x4*)((As_) + (aoff0 ^ xo));                          \
            i32x4 a1 = *(const i32x4*)((As_) + (aoff1 ^ xo));                          \
            i32x4 b0 = *(const i32x4*)((Bs_) + (boff0 ^ xo));                          \
            i32x4 b1 = *(const i32x4*)((Bs_) + (boff1 ^ xo));                          \
            i32x4 b2 = *(const i32x4*)((Bs_) + (boff2 ^ xo));                          \
            i32x4 b3 = *(const i32x4*)((Bs_) + (boff3 ^ xo));                          \
            acc[0][0] = __builtin_amdgcn_mfma_i32_32x32x32_i8(a0, b0, acc[0][0], 0, 0, 0); \
            acc[0][1] = __builtin_amdgcn_mfma_i32_32x32x32_i8(a0, b1, acc[0][1], 0, 0, 0); \
            acc[0][2] = __builtin_amdgcn_mfma_i32_32x32x32_i8(a0, b2, acc[0][2], 0, 0, 0); \
            acc[0][3] = __builtin_amdgcn_mfma_i32_32x32x32_i8(a0, b3, acc[0][3], 0, 0, 0); \
            acc[1][0] = __builtin_amdgcn_mfma_i32_32x32x32_i8(a1, b0, acc[1][0], 0, 0, 0); \
            acc[1][1] = __builtin_amdgcn_mfma_i32_32x32x32_i8(a1, b1, acc[1][1], 0, 0, 0); \
            acc[1][2] = __builtin_amdgcn_mfma_i32_32x32x32_i8(a1, b2, acc[1][2], 0, 0, 0); \
            acc[1][3] = __builtin_amdgcn_mfma_i32_32x32x32_i8(a1, b3, acc[1][3], 0, 0, 0); \
        }                                                                              \
    } while (0)

    // ---- prologue ----
    STAGE(As0, Bs0, 0);
    VMC0;
    BARRIER;

    // ---- main loop: 8 K-tiles of 64 ----
    for (int i = 0; i < 4; ++i) {
        STAGE(As1, Bs1, 2 * i + 1);
        COMPUTE(As0, Bs0);
        VMC0;
        BARRIER;
        if (i < 3) STAGE(As0, Bs0, 2 * i + 2);
        COMPUTE(As1, Bs1);
        if (i < 3) { VMC0; BARRIER; }
    }

    // ---- epilogue ----
    // C/D 32x32 layout: col = lane&31, row = (r&3) + 8*(r>>2) + 4*(lane>>5)
    const bool diag = ((br >> 1) == bc);
    const int  poff = (br & 1) * 128;
    unsigned* rbuf = (unsigned*)As0;   // [128][2] row winners
    unsigned* cbuf = (unsigned*)Bs0;   // [256][2] col winners
    const int cl0 = wc * 128 + l31;

    // ROW view: winner over this wave's 128 cols, per row (DPP reduce)
#pragma unroll
    for (int m = 0; m < 2; ++m) {
#pragma unroll
        for (int r = 0; r < 16; ++r) {
            int rl = wr * 64 + m * 32 + (r & 3) + 8 * (r >> 2) + 4 * h;
            unsigned p = 0;
#pragma unroll
            for (int n = 0; n < 4; ++n) {
                int cl = cl0 + n * 32;
                unsigned q = ((unsigned)(acc[m][n][r] + BIAS) << 8)
                           | (unsigned)(255 - cl);
                if (diag && cl == rl + poff) q = 0;
                p = umax32(p, q);
            }
            p = dppmax<0xB1>(p);    // quad_perm xor1
            p = dppmax<0x4E>(p);    // quad_perm xor2
            p = dppmax<0x141>(p);   // row_half_mirror (xor 8 within 16)
            p = dppmax<0x140>(p);   // row_mirror (xor 16 within 32... full row)
            p = umax32(p, (unsigned)__shfl_xor((int)p, 16, 64));
            if (l31 == 0) rbuf[rl * 2 + wc] = p;
        }
    }
    // COL view: winner over this wave's 64 rows, per col (in-register)
#pragma unroll
    for (int n = 0; n < 4; ++n) {
        int cl = cl0 + n * 32;
        unsigned bst = 0;
#pragma unroll
        for (int m = 0; m < 2; ++m) {
#pragma unroll
            for (int r = 0; r < 16; ++r) {
                int base = wr * 64 + m * 32 + (r & 3) + 8 * (r >> 2);   // true rel = base + 4h
                unsigned q = ((unsigned)(acc[m][n][r] + BIAS) << 7)
                           | (unsigned)(127 - base);
                if (diag && cl == base + 4 * h + poff) q = 0;
                bst = umax32(bst, q);
            }
        }
        bst -= (unsigned)(4 * h);   // all candidates in-lane share h
        bst = umax32(bst, (unsigned)__shfl_xor((int)bst, 32, 64));
        if (h == 0) cbuf[cl * 2 + wr] = bst;
    }
    __syncthreads();
    // coalesced PT stores
    if (tid < 128) {
        unsigned w = umax32(rbuf[tid * 2], rbuf[tid * 2 + 1]);
        PT[(size_t)bc * N_PTS + arow0 + tid] = w;               // slots 0..63: row view
    }
    {
        unsigned w = umax32(cbuf[tid * 2], cbuf[tid * 2 + 1]);
        PT[(size_t)(NCB + br) * N_PTS + bcol0 + tid] = w;       // slots 64..191: col view
    }
#undef STAGE
#undef COMPUTE
}

// =====================================================================
// Kernel 3: reduce PT slots -> nb[row]. Unwritten slots are memset-0 and
// always lose (real packed >= 130560<<7). Tie rule -> smallest global j.
// =====================================================================
__global__ void k_reduceP(const unsigned* __restrict__ PT, int* __restrict__ nb) {
    int r = (int)blockIdx.x * 256 + (int)threadIdx.x;
    u64 bst = 0;
#pragma unroll 4
    for (int bc = 0; bc < NCB; ++bc) {
        unsigned p = PT[(size_t)bc * N_PTS + r];
        unsigned j = bc * 256 + 255 - (p & 255);
        bst = pmax64(bst, ((u64)(p >> 8) << 14) | (16383 - j));
    }
#pragma unroll 4
    for (int br = 0; br < NRB; ++br) {
        unsigned p = PT[(size_t)(NCB + br) * N_PTS + r];
        unsigned j = br * 128 + 127 - (p & 127);
        bst = pmax64(bst, ((u64)(p >> 7) << 14) | (16383 - j));
    }
    nb[r] = 16383 - (int)(bst & 16383);
}

// =====================================================================
// Kernel 4: per-row fp32 loss term: log(||x_r - x_I + 1e-6|| + 1e-8)
// =====================================================================
__global__ void k_rowloss(const float* __restrict__ x,
                          const int* __restrict__ nb,
                          float* __restrict__ rowloss) {
    int wave = (int)threadIdx.x >> 6, lane = (int)threadIdx.x & 63;
    int r = (int)blockIdx.x * 4 + wave;
    int nbi = nb[r];
    const float4* xr = (const float4*)(x + (size_t)r   * DIM);
    const float4* xn = (const float4*)(x + (size_t)nbi * DIM);
    float s = 0.f;
#pragma unroll
    for (int i = 0; i < 2; ++i) {
        float4 a = xr[lane * 2 + i];
        float4 b = xn[lane * 2 + i];
        float d0 = a.x - b.x + 1e-6f;
        float d1 = a.y - b.y + 1e-6f;
        float d2 = a.z - b.z + 1e-6f;
        float d3 = a.w - b.w + 1e-6f;
        s = fmaf(d0, d0, s); s = fmaf(d1, d1, s);
        s = fmaf(d2, d2, s); s = fmaf(d3, d3, s);
    }
#pragma unroll
    for (int m = 1; m < 64; m <<= 1) s += __shfl_xor(s, m, 64);
    if (lane == 0) rowloss[r] = logf(sqrtf(s) + 1e-8f);
}

// =====================================================================
// Kernel 5: deterministic single-block reduction -> scalar
// =====================================================================
__global__ void k_reduce(const float* __restrict__ rowloss, float* __restrict__ out) {
    __shared__ float sm[256];
    float s = 0.f;
    for (int i = (int)threadIdx.x; i < N_PTS; i += 256) s += rowloss[i];
    sm[threadIdx.x] = s;
    __syncthreads();
    for (int st = 128; st > 0; st >>= 1) {
        if ((int)threadIdx.x < st) sm[threadIdx.x] += sm[threadIdx.x + st];
        __syncthreads();
    }
    if (threadIdx.x == 0) out[0] = -0.1f * sm[0] / (float)N_PTS;
}

extern "C" void kernel_launch(void* const* d_in, const int* in_sizes, int n_in,
                              void* d_out, int out_size, void* d_ws, size_t ws_size,
                              hipStream_t stream) {
    const float* x = (const float*)d_in[0];
    float* out = (float*)d_out;
    char* ws = (char*)d_ws;

    // layout: [xq 8MB][PT (64+128)*16384 u32 = 12.6MB][nb 64KB][rowloss 64KB]
    const size_t xqB = (size_t)N_PTS * DIM;                   // 8 MB
    const size_t ptB = (size_t)(NCB + NRB) * N_PTS * 4;       // 12.58 MB
    char*     xq = ws;
    unsigned* PT = (unsigned*)(ws + xqB);
    int*      nb = (int*)(ws + xqB + ptB);
    float*    rowloss = (float*)(ws + xqB + ptB + (size_t)N_PTS * 4);

    k_quant<<<dim3(4096), dim3(256), 0, stream>>>(x, xq);
    (void)hipMemsetAsync(PT, 0, ptB, stream);
    k_gemm_argmax<<<dim3(NTILE), dim3(256), 0, stream>>>(xq, PT);
    k_reduceP<<<dim3(N_PTS / 256), dim3(256), 0, stream>>>(PT, nb);
    k_rowloss<<<dim3(N_PTS / 4), dim3(256), 0, stream>>>(x, nb, rowloss);
    k_reduce<<<dim3(1), dim3(256), 0, stream>>>(rowloss, out);
}

// Round 9
// 173.206 us; speedup vs baseline: 2.0416x; 1.0567x over previous
//
#include <hip/hip_runtime.h>
#include <hip/hip_bf16.h>
#include <math.h>

#define N_PTS 16384
#define DIM   512
#define BMR   128               // tile rows
#define BNC   256               // tile cols
#define BK    64                // i8: 64-byte LDS rows
#define NRB   (N_PTS / BMR)     // 128 row-blocks
#define NCB   (N_PTS / BNC)     // 64 col-blocks
#define NTILE 4160              // sum_{g=0}^{63} 2*(64-g)
#define QSCALE 23.0f
#define BIAS   (1 << 23)        // |dot| <= 512*127^2 = 8258048 < 2^23

typedef int i32x4  __attribute__((ext_vector_type(4)));
typedef int i32x16 __attribute__((ext_vector_type(16)));
typedef unsigned long long u64;

#define VMC3    asm volatile("s_waitcnt vmcnt(3)" ::: "memory")
#define VMC0    asm volatile("s_waitcnt vmcnt(0)" ::: "memory")
#define BARRIER __builtin_amdgcn_s_barrier()

__device__ __forceinline__ u64 pmax64(u64 a, u64 b) { return a > b ? a : b; }
__device__ __forceinline__ unsigned umax32(unsigned a, unsigned b) { return a > b ? a : b; }
// DPP-based max step (VALU, stays off the LDS crossbar). CTRL must be literal.
template <int CTRL>
__device__ __forceinline__ unsigned dppmax(unsigned p) {
    int t = __builtin_amdgcn_update_dpp(0, (int)p, CTRL, 0xF, 0xF, true);
    return umax32(p, (unsigned)t);
}
__device__ __forceinline__ void gll(const char* g, char* l) {
    __builtin_amdgcn_global_load_lds(
        (const __attribute__((address_space(1))) void*)g,
        (__attribute__((address_space(3))) void*)l, 16, 0, 0);
}

// =====================================================================
// Kernel 1: fp32 -> int8 quantize + zero PT (fused, drops memset launch)
// =====================================================================
__global__ void k_quant(const float* __restrict__ x, char* __restrict__ xq,
                        int4* __restrict__ PTz) {
    int t = blockIdx.x * blockDim.x + threadIdx.x;   // 0..1048575
    size_t e = (size_t)t * 8;
    float4 f0 = *(const float4*)(x + e);
    float4 f1 = *(const float4*)(x + e + 4);
    auto q8 = [](float v) -> int {
        return (int)rintf(fminf(fmaxf(v * QSCALE, -127.0f), 127.0f));
    };
    int lo = (q8(f0.x) & 255) | ((q8(f0.y) & 255) << 8)
           | ((q8(f0.z) & 255) << 16) | ((q8(f0.w) & 255) << 24);
    int hi = (q8(f1.x) & 255) | ((q8(f1.y) & 255) << 8)
           | ((q8(f1.z) & 255) << 16) | ((q8(f1.w) & 255) << 24);
    int2 o; o.x = lo; o.y = hi;
    *(int2*)(xq + e) = o;
    // PT = (64+128)*16384 u32 = 786432 int4s; threads 0..786431 zero one each
    if (t < (NCB + NRB) * N_PTS / 4) {
        int4 z; z.x = 0; z.y = 0; z.z = 0; z.w = 0;
        PTz[t] = z;
    }
}

// =====================================================================
// Kernel 2: 128x256 tiles (bc >= br>>1; below-diagonal overlap cells are
// symmetric duplicates, harmless for max), 8 waves in 2x4 grid, wave tile
// 64x64 (acc 2x2 of 32x32 -> 64 AGPR, ~120 regs total -> 4 waves/SIMD),
// i8 MFMA, BK=64, TRIPLE-buffered with counted vmcnt(3) (T4: loads get a
// ~2-phase latency window, never drained to 0 mid-loop), XOR-swizzled LDS.
// Epilogue: DPP row winners + in-register col winners -> PT slots.
// =====================================================================
__global__ __launch_bounds__(512, 4)
void k_gemm_argmax(const char* __restrict__ xq, unsigned* __restrict__ PT) {
    __shared__ __align__(16) char As0[BMR * BK], As1[BMR * BK], As2[BMR * BK];   // 8 KB ea
    __shared__ __align__(16) char Bs0[BNC * BK], Bs1[BNC * BK], Bs2[BNC * BK];   // 16 KB ea

    // T1: XCD swizzle (4160 % 8 == 0)
    int t0i = (int)blockIdx.x;
    int t = (t0i & 7) * (NTILE / 8) + (t0i >> 3);

    // decode t -> (br, bc): groups g = br>>1, S(g) = g*(129-g)
    int g = (int)((129.0f - sqrtf(16641.0f - 4.0f * (float)t)) * 0.5f);
    while (g * (129 - g) > t) --g;
    while ((g + 1) * (128 - g) <= t) ++g;
    int u = t - g * (129 - g);
    int bc = g + (u >> 1);
    int br = 2 * g + (u & 1);

    const int tid  = (int)threadIdx.x;
    const int lane = tid & 63;
    const int wave = tid >> 6;       // 0..7
    const int wr   = wave >> 2;      // 0/1 -> 64-row band
    const int wc   = wave & 3;       // 0..3 -> 64-col band
    const int l31  = lane & 31;
    const int h    = lane >> 5;

    const int arow0 = br * BMR;
    const int bcol0 = bc * BNC;

    // staging: A = 512 chunks (1/thread), B = 1024 chunks (2/thread)
    // LDS linear; SOURCE inverse-swizzled: col16 = (tid&3) ^ ((row>>1)&3)
    const int srow   = tid >> 2;                        // 0..127
    const int scol16 = (tid & 3) ^ ((tid >> 3) & 3);
    const char* gA  = xq + (size_t)(arow0 + srow)       * DIM + scol16 * 16;
    const char* gB0 = xq + (size_t)(bcol0 + srow)       * DIM + scol16 * 16;
    const char* gB1 = xq + (size_t)(bcol0 + 128 + srow) * DIM + scol16 * 16;
    const int cbA  = (tid & ~63) * 16;
    const int cbB0 = cbA;
    const int cbB1 = (512 + (tid & ~63)) * 16;

#define STAGE(Ad, Bd, kt)                                                \
    do {                                                                 \
        int ko = (kt) * BK;                                              \
        gll(gA + ko, (Ad) + cbA);                                        \
        gll(gB0 + ko, (Bd) + cbB0);                                      \
        gll(gB1 + ko, (Bd) + cbB1);                                      \
    } while (0)

    // fragment read byte offsets: row*64 + ((q ^ ((row>>1)&3))<<4), q=s*2+h
    const int rw = (l31 >> 1) & 3;
    const int aoff0 = (wr * 64 + 0  + l31) * 64 + ((h ^ rw) << 4);
    const int aoff1 = (wr * 64 + 32 + l31) * 64 + ((h ^ rw) << 4);
    const int boff0 = (wc * 64 + 0  + l31) * 64 + ((h ^ rw) << 4);
    const int boff1 = (wc * 64 + 32 + l31) * 64 + ((h ^ rw) << 4);

    i32x16 acc[2][2] = {};

#define COMPUTE(As_, Bs_)                                                              \
    do {                                                                               \
        _Pragma("unroll")                                                              \
        for (int s = 0; s < 2; ++s) {                                                  \
            const int xo = s * 32;                                                     \
            i32x4 a0 = *(const i32x4*)((As_) + (aoff0 ^ xo));                          \
            i32x4 a1 = *(const i32x4*)((As_) + (aoff1 ^ xo));                          \
            i32x4 b0 = *(const i32x4*)((Bs_) + (boff0 ^ xo));                          \
            i32x4 b1 = *(const i32x4*)((Bs_) + (boff1 ^ xo));                          \
            acc[0][0] = __builtin_amdgcn_mfma_i32_32x32x32_i8(a0, b0, acc[0][0], 0, 0, 0); \
            acc[0][1] = __builtin_amdgcn_mfma_i32_32x32x32_i8(a0, b1, acc[0][1], 0, 0, 0); \
            acc[1][0] = __builtin_amdgcn_mfma_i32_32x32x32_i8(a1, b0, acc[1][0], 0, 0, 0); \
            acc[1][1] = __builtin_amdgcn_mfma_i32_32x32x32_i8(a1, b1, acc[1][1], 0, 0, 0); \
        }                                                                              \
    } while (0)

    // ---- prologue: stage tiles 0,1 (3 gll each); wait tile 0 only ----
    STAGE(As0, Bs0, 0);
    STAGE(As1, Bs1, 1);
    VMC3;                    // 6 outstanding -> 3: tile 0 landed, tile 1 in flight
    BARRIER;

    // ---- 8 K-tiles, buffers rotate 0,1,2; vmcnt(3) = counted, never 0 ----
    STAGE(As2, Bs2, 2); COMPUTE(As0, Bs0); VMC3; BARRIER;   // t0: tile1 landed
    STAGE(As0, Bs0, 3); COMPUTE(As1, Bs1); VMC3; BARRIER;   // t1: tile2 landed
    STAGE(As1, Bs1, 4); COMPUTE(As2, Bs2); VMC3; BARRIER;   // t2
    STAGE(As2, Bs2, 5); COMPUTE(As0, Bs0); VMC3; BARRIER;   // t3
    STAGE(As0, Bs0, 6); COMPUTE(As1, Bs1); VMC3; BARRIER;   // t4
    STAGE(As1, Bs1, 7); COMPUTE(As2, Bs2); VMC3; BARRIER;   // t5: tile6 landed
    COMPUTE(As0, Bs0);  VMC0; BARRIER;                      // t6: drain tile 7
    COMPUTE(As1, Bs1);                                      // t7 (no stage, no drain)

    // ---- epilogue ----
    // C/D 32x32 layout: col = lane&31, row = (r&3) + 8*(r>>2) + 4*(lane>>5)
    const bool diag = ((br >> 1) == bc);
    const int  poff = (br & 1) * 128;
    unsigned* rbuf = (unsigned*)As0;   // [128][4] row winners (As0 quiesced at t6 barrier)
    unsigned* cbuf = (unsigned*)Bs0;   // [256][2] col winners (Bs0 quiesced at t6 barrier)
    const int cl0 = wc * 64 + l31;

    // ROW view: winner over this wave's 64 cols, per row (DPP reduce in h-half)
#pragma unroll
    for (int m = 0; m < 2; ++m) {
#pragma unroll
        for (int r = 0; r < 16; ++r) {
            int rl = wr * 64 + m * 32 + (r & 3) + 8 * (r >> 2) + 4 * h;
            unsigned p = 0;
#pragma unroll
            for (int n = 0; n < 2; ++n) {
                int cl = cl0 + n * 32;
                unsigned q = ((unsigned)(acc[m][n][r] + BIAS) << 8)
                           | (unsigned)(255 - cl);
                if (diag && cl == rl + poff) q = 0;
                p = umax32(p, q);
            }
            p = dppmax<0xB1>(p);    // quad_perm xor1
            p = dppmax<0x4E>(p);    // quad_perm xor2
            p = dppmax<0x141>(p);   // row_half_mirror
            p = dppmax<0x140>(p);   // row_mirror
            p = umax32(p, (unsigned)__shfl_xor((int)p, 16, 64));
            if (l31 == 0) rbuf[rl * 4 + wc] = p;
        }
    }
    // COL view: winner over this wave's 64 rows, per col (in-register)
#pragma unroll
    for (int n = 0; n < 2; ++n) {
        int cl = cl0 + n * 32;
        unsigned bst = 0;
#pragma unroll
        for (int m = 0; m < 2; ++m) {
#pragma unroll
            for (int r = 0; r < 16; ++r) {
                int base = wr * 64 + m * 32 + (r & 3) + 8 * (r >> 2);   // true rel = base + 4h
                unsigned q = ((unsigned)(acc[m][n][r] + BIAS) << 7)
                           | (unsigned)(127 - base);
                if (diag && cl == base + 4 * h + poff) q = 0;
                bst = umax32(bst, q);
            }
        }
        bst -= (unsigned)(4 * h);   // all candidates in-lane share h
        bst = umax32(bst, (unsigned)__shfl_xor((int)bst, 32, 64));
        if (h == 0) cbuf[cl * 2 + wr] = bst;
    }
    __syncthreads();
    // coalesced PT stores
    if (tid < 128) {
        unsigned w = umax32(umax32(rbuf[tid * 4], rbuf[tid * 4 + 1]),
                            umax32(rbuf[tid * 4 + 2], rbuf[tid * 4 + 3]));
        PT[(size_t)bc * N_PTS + arow0 + tid] = w;               // slots 0..63: row view
    } else if (tid < 384) {
        int c = tid - 128;
        unsigned w = umax32(cbuf[c * 2], cbuf[c * 2 + 1]);
        PT[(size_t)(NCB + br) * N_PTS + bcol0 + c] = w;         // slots 64..191: col view
    }
#undef STAGE
#undef COMPUTE
}

// =====================================================================
// Kernel 3: reduce PT slots -> nb[row]. Unwritten slots are zeroed and
// always lose (real packed >= 130560<<7). Tie rule -> smallest global j.
// =====================================================================
__global__ void k_reduceP(const unsigned* __restrict__ PT, int* __restrict__ nb) {
    int r = (int)blockIdx.x * 256 + (int)threadIdx.x;
    u64 bst = 0;
#pragma unroll 4
    for (int bc = 0; bc < NCB; ++bc) {
        unsigned p = PT[(size_t)bc * N_PTS + r];
        unsigned j = bc * 256 + 255 - (p & 255);
        bst = pmax64(bst, ((u64)(p >> 8) << 14) | (16383 - j));
    }
#pragma unroll 4
    for (int br = 0; br < NRB; ++br) {
        unsigned p = PT[(size_t)(NCB + br) * N_PTS + r];
        unsigned j = br * 128 + 127 - (p & 127);
        bst = pmax64(bst, ((u64)(p >> 7) << 14) | (16383 - j));
    }
    nb[r] = 16383 - (int)(bst & 16383);
}

// =====================================================================
// Kernel 4: per-row fp32 loss term: log(||x_r - x_I + 1e-6|| + 1e-8)
// =====================================================================
__global__ void k_rowloss(const float* __restrict__ x,
                          const int* __restrict__ nb,
                          float* __restrict__ rowloss) {
    int wave = (int)threadIdx.x >> 6, lane = (int)threadIdx.x & 63;
    int r = (int)blockIdx.x * 4 + wave;
    int nbi = nb[r];
    const float4* xr = (const float4*)(x + (size_t)r   * DIM);
    const float4* xn = (const float4*)(x + (size_t)nbi * DIM);
    float s = 0.f;
#pragma unroll
    for (int i = 0; i < 2; ++i) {
        float4 a = xr[lane * 2 + i];
        float4 b = xn[lane * 2 + i];
        float d0 = a.x - b.x + 1e-6f;
        float d1 = a.y - b.y + 1e-6f;
        float d2 = a.z - b.z + 1e-6f;
        float d3 = a.w - b.w + 1e-6f;
        s = fmaf(d0, d0, s); s = fmaf(d1, d1, s);
        s = fmaf(d2, d2, s); s = fmaf(d3, d3, s);
    }
#pragma unroll
    for (int m = 1; m < 64; m <<= 1) s += __shfl_xor(s, m, 64);
    if (lane == 0) rowloss[r] = logf(sqrtf(s) + 1e-8f);
}

// =====================================================================
// Kernel 5: deterministic single-block reduction -> scalar
// =====================================================================
__global__ void k_reduce(const float* __restrict__ rowloss, float* __restrict__ out) {
    __shared__ float sm[256];
    float s = 0.f;
    for (int i = (int)threadIdx.x; i < N_PTS; i += 256) s += rowloss[i];
    sm[threadIdx.x] = s;
    __syncthreads();
    for (int st = 128; st > 0; st >>= 1) {
        if ((int)threadIdx.x < st) sm[threadIdx.x] += sm[threadIdx.x + st];
        __syncthreads();
    }
    if (threadIdx.x == 0) out[0] = -0.1f * sm[0] / (float)N_PTS;
}

extern "C" void kernel_launch(void* const* d_in, const int* in_sizes, int n_in,
                              void* d_out, int out_size, void* d_ws, size_t ws_size,
                              hipStream_t stream) {
    const float* x = (const float*)d_in[0];
    float* out = (float*)d_out;
    char* ws = (char*)d_ws;

    // layout: [xq 8MB][PT (64+128)*16384 u32 = 12.6MB][nb 64KB][rowloss 64KB]
    const size_t xqB = (size_t)N_PTS * DIM;                   // 8 MB
    const size_t ptB = (size_t)(NCB + NRB) * N_PTS * 4;       // 12.58 MB
    char*     xq = ws;
    unsigned* PT = (unsigned*)(ws + xqB);
    int*      nb = (int*)(ws + xqB + ptB);
    float*    rowloss = (float*)(ws + xqB + ptB + (size_t)N_PTS * 4);

    k_quant<<<dim3(4096), dim3(256), 0, stream>>>(x, xq, (int4*)PT);
    k_gemm_argmax<<<dim3(NTILE), dim3(512), 0, stream>>>(xq, PT);
    k_reduceP<<<dim3(N_PTS / 256), dim3(256), 0, stream>>>(PT, nb);
    k_rowloss<<<dim3(N_PTS / 4), dim3(256), 0, stream>>>(x, nb, rowloss);
    k_reduce<<<dim3(1), dim3(256), 0, stream>>>(rowloss, out);
}

// Round 10
// 163.874 us; speedup vs baseline: 2.1578x; 1.0569x over previous
//
#include <hip/hip_runtime.h>
#include <hip/hip_bf16.h>
#include <math.h>

#define N_PTS 16384
#define DIM   512
#define BMR   128               // tile rows
#define BNC   256               // tile cols
#define BK    64                // i8: 64-byte LDS rows
#define NRB   (N_PTS / BMR)     // 128 row-blocks
#define NCB   (N_PTS / BNC)     // 64 col-blocks
#define NTILE 4160              // sum_{g=0}^{63} 2*(64-g)
#define QSCALE 23.0f
#define BIAS   (1 << 23)        // |dot| <= 512*127^2 = 8258048 < 2^23

typedef int i32x4  __attribute__((ext_vector_type(4)));
typedef int i32x16 __attribute__((ext_vector_type(16)));
typedef unsigned long long u64;

#define VMC3    asm volatile("s_waitcnt vmcnt(3)" ::: "memory")
#define VMC0    asm volatile("s_waitcnt vmcnt(0)" ::: "memory")
#define BARRIER __builtin_amdgcn_s_barrier()

__device__ __forceinline__ u64 pmax64(u64 a, u64 b) { return a > b ? a : b; }
__device__ __forceinline__ unsigned umax32(unsigned a, unsigned b) { return a > b ? a : b; }
// DPP-based max step (VALU, off the LDS crossbar). CTRL must be literal.
// Chain xor1 (0xB1), xor2 (0x4E), half_mirror=xor7 (0x141), mirror=xor15
// (0x140): after all 4, every aligned 16-lane group holds its group max.
template <int CTRL>
__device__ __forceinline__ unsigned dppmax(unsigned p) {
    int t = __builtin_amdgcn_update_dpp(0, (int)p, CTRL, 0xF, 0xF, true);
    return umax32(p, (unsigned)t);
}
__device__ __forceinline__ void gll(const char* g, char* l) {
    __builtin_amdgcn_global_load_lds(
        (const __attribute__((address_space(1))) void*)g,
        (__attribute__((address_space(3))) void*)l, 16, 0, 0);
}

// =====================================================================
// Kernel 1: fp32 -> int8 quantize (PT zeroing no longer needed: k_reduceP
// only reads slots that are written by construction)
// =====================================================================
__global__ void k_quant(const float* __restrict__ x, char* __restrict__ xq) {
    int t = blockIdx.x * blockDim.x + threadIdx.x;
    size_t e = (size_t)t * 8;
    float4 f0 = *(const float4*)(x + e);
    float4 f1 = *(const float4*)(x + e + 4);
    auto q8 = [](float v) -> int {
        return (int)rintf(fminf(fmaxf(v * QSCALE, -127.0f), 127.0f));
    };
    int lo = (q8(f0.x) & 255) | ((q8(f0.y) & 255) << 8)
           | ((q8(f0.z) & 255) << 16) | ((q8(f0.w) & 255) << 24);
    int hi = (q8(f1.x) & 255) | ((q8(f1.y) & 255) << 8)
           | ((q8(f1.z) & 255) << 16) | ((q8(f1.w) & 255) << 24);
    int2 o; o.x = lo; o.y = hi;
    *(int2*)(xq + e) = o;
}

// =====================================================================
// Kernel 2: 128x256 tiles (bc >= br>>1), 8 waves 2x4, wave tile 64x64,
// i8 MFMA, BK=64, triple-buffer counted vmcnt(3) (R9-verified main loop).
// Epilogue: swizzle-free — 4-DPP row reduce writes two 16-group partials,
// col view writes both h partials; PT-store threads merge. lshl_add packs,
// block-uniform diag specialization.
// =====================================================================
__global__ __launch_bounds__(512, 4)
void k_gemm_argmax(const char* __restrict__ xq, unsigned* __restrict__ PT) {
    __shared__ __align__(16) char As0[BMR * BK], As1[BMR * BK], As2[BMR * BK];   // 8 KB ea
    __shared__ __align__(16) char Bs0[BNC * BK], Bs1[BNC * BK], Bs2[BNC * BK];   // 16 KB ea

    // T1: XCD swizzle (4160 % 8 == 0)
    int t0i = (int)blockIdx.x;
    int t = (t0i & 7) * (NTILE / 8) + (t0i >> 3);

    // decode t -> (br, bc): groups g = br>>1, S(g) = g*(129-g)
    int g = (int)((129.0f - sqrtf(16641.0f - 4.0f * (float)t)) * 0.5f);
    while (g * (129 - g) > t) --g;
    while ((g + 1) * (128 - g) <= t) ++g;
    int u = t - g * (129 - g);
    int bc = g + (u >> 1);
    int br = 2 * g + (u & 1);

    const int tid  = (int)threadIdx.x;
    const int lane = tid & 63;
    const int wave = tid >> 6;       // 0..7
    const int wr   = wave >> 2;      // 0/1 -> 64-row band
    const int wc   = wave & 3;       // 0..3 -> 64-col band
    const int l31  = lane & 31;
    const int h    = lane >> 5;

    const int arow0 = br * BMR;
    const int bcol0 = bc * BNC;

    // staging: A = 512 chunks (1/thread), B = 1024 chunks (2/thread)
    // LDS linear; SOURCE inverse-swizzled: col16 = (tid&3) ^ ((row>>1)&3)
    const int srow   = tid >> 2;                        // 0..127
    const int scol16 = (tid & 3) ^ ((tid >> 3) & 3);
    const char* gA  = xq + (size_t)(arow0 + srow)       * DIM + scol16 * 16;
    const char* gB0 = xq + (size_t)(bcol0 + srow)       * DIM + scol16 * 16;
    const char* gB1 = xq + (size_t)(bcol0 + 128 + srow) * DIM + scol16 * 16;
    const int cbA  = (tid & ~63) * 16;
    const int cbB0 = cbA;
    const int cbB1 = (512 + (tid & ~63)) * 16;

#define STAGE(Ad, Bd, kt)                                                \
    do {                                                                 \
        int ko = (kt) * BK;                                              \
        gll(gA + ko, (Ad) + cbA);                                        \
        gll(gB0 + ko, (Bd) + cbB0);                                      \
        gll(gB1 + ko, (Bd) + cbB1);                                      \
    } while (0)

    // fragment read byte offsets: row*64 + ((q ^ ((row>>1)&3))<<4), q=s*2+h
    const int rw = (l31 >> 1) & 3;
    const int aoff0 = (wr * 64 + 0  + l31) * 64 + ((h ^ rw) << 4);
    const int aoff1 = (wr * 64 + 32 + l31) * 64 + ((h ^ rw) << 4);
    const int boff0 = (wc * 64 + 0  + l31) * 64 + ((h ^ rw) << 4);
    const int boff1 = (wc * 64 + 32 + l31) * 64 + ((h ^ rw) << 4);

    i32x16 acc[2][2] = {};

#define COMPUTE(As_, Bs_)                                                              \
    do {                                                                               \
        _Pragma("unroll")                                                              \
        for (int s = 0; s < 2; ++s) {                                                  \
            const int xo = s * 32;                                                     \
            i32x4 a0 = *(const i32x4*)((As_) + (aoff0 ^ xo));                          \
            i32x4 a1 = *(const i32x4*)((As_) + (aoff1 ^ xo));                          \
            i32x4 b0 = *(const i32x4*)((Bs_) + (boff0 ^ xo));                          \
            i32x4 b1 = *(const i32x4*)((Bs_) + (boff1 ^ xo));                          \
            acc[0][0] = __builtin_amdgcn_mfma_i32_32x32x32_i8(a0, b0, acc[0][0], 0, 0, 0); \
            acc[0][1] = __builtin_amdgcn_mfma_i32_32x32x32_i8(a0, b1, acc[0][1], 0, 0, 0); \
            acc[1][0] = __builtin_amdgcn_mfma_i32_32x32x32_i8(a1, b0, acc[1][0], 0, 0, 0); \
            acc[1][1] = __builtin_amdgcn_mfma_i32_32x32x32_i8(a1, b1, acc[1][1], 0, 0, 0); \
        }                                                                              \
    } while (0)

    // ---- prologue: stage tiles 0,1; wait tile 0 only ----
    STAGE(As0, Bs0, 0);
    STAGE(As1, Bs1, 1);
    VMC3;
    BARRIER;

    // ---- 8 K-tiles, buffers rotate 0,1,2; vmcnt(3) counted, never 0 mid-loop ----
    STAGE(As2, Bs2, 2); COMPUTE(As0, Bs0); VMC3; BARRIER;
    STAGE(As0, Bs0, 3); COMPUTE(As1, Bs1); VMC3; BARRIER;
    STAGE(As1, Bs1, 4); COMPUTE(As2, Bs2); VMC3; BARRIER;
    STAGE(As2, Bs2, 5); COMPUTE(As0, Bs0); VMC3; BARRIER;
    STAGE(As0, Bs0, 6); COMPUTE(As1, Bs1); VMC3; BARRIER;
    STAGE(As1, Bs1, 7); COMPUTE(As2, Bs2); VMC3; BARRIER;
    COMPUTE(As0, Bs0);  VMC0; BARRIER;          // after this barrier As0/Bs0 quiesced
    COMPUTE(As1, Bs1);                          // t7

    // ---- epilogue (swizzle-free) ----
    // C/D 32x32 layout: col = lane&31, row = (r&3) + 8*(r>>2) + 4*(lane>>5)
    const bool diag = ((br >> 1) == bc);
    const int  poff = (br & 1) * 128;
    unsigned* rbuf = (unsigned*)As0;   // [128][8] row partials (4 KB)
    unsigned* cbuf = (unsigned*)Bs0;   // [256][4] col partials (4 KB)
    const int cl0 = wc * 64 + l31;
    const int s16 = (l31 >> 4) & 1;            // which 16-group this lane is in
    // per-n pack constants: q = (acc<<8) + C,  C = (BIAS<<8) | (255-cl)
    const unsigned Cr0 = ((unsigned)BIAS << 8) | (unsigned)(255 - cl0);
    const unsigned Cr1 = Cr0 - 32;

    auto epi = [&](bool dg) {
        // ROW view: per row, max over wave's 64 cols; 4-DPP -> 2 partials
#pragma unroll
        for (int m = 0; m < 2; ++m) {
#pragma unroll
            for (int r = 0; r < 16; ++r) {
                int rl = wr * 64 + m * 32 + (r & 3) + 8 * (r >> 2) + 4 * h;
                unsigned q0 = ((unsigned)acc[m][0][r] << 8) + Cr0;
                unsigned q1 = ((unsigned)acc[m][1][r] << 8) + Cr1;
                if (dg && cl0 == rl + poff) q0 = 0;
                if (dg && cl0 + 32 == rl + poff) q1 = 0;
                unsigned p = umax32(q0, q1);
                p = dppmax<0xB1>(p);    // xor1
                p = dppmax<0x4E>(p);    // xor2
                p = dppmax<0x141>(p);   // half_mirror (xor7 -> aligned 8)
                p = dppmax<0x140>(p);   // mirror (xor15 -> aligned 16)
                if ((l31 & 15) == 0) rbuf[rl * 8 + wc * 2 + s16] = p;
            }
        }
        // COL view: per col, in-register max over wave's 64 rows; both h write
#pragma unroll
        for (int n = 0; n < 2; ++n) {
            int cl = cl0 + n * 32;
            unsigned bst = 0;
#pragma unroll
            for (int m = 0; m < 2; ++m) {
#pragma unroll
                for (int r = 0; r < 16; ++r) {
                    int base = wr * 64 + m * 32 + (r & 3) + 8 * (r >> 2);  // true rel = base+4h
                    unsigned q = ((unsigned)acc[m][n][r] << 7)
                               + (((unsigned)BIAS << 7) | (unsigned)(127 - base));
                    if (dg && cl == base + 4 * h + poff) q = 0;
                    bst = umax32(bst, q);
                }
            }
            bst -= (unsigned)(4 * h);   // correct idx bits: 127-(base+4h)
            cbuf[cl * 4 + wr * 2 + h] = bst;
        }
    };
    if (diag) epi(true); else epi(false);

    __syncthreads();
    // coalesced PT stores
    if (tid < 128) {
        const unsigned* rb = rbuf + tid * 8;
        unsigned w = umax32(umax32(umax32(rb[0], rb[1]), umax32(rb[2], rb[3])),
                            umax32(umax32(rb[4], rb[5]), umax32(rb[6], rb[7])));
        PT[(size_t)bc * N_PTS + arow0 + tid] = w;               // row-view slot bc
    } else if (tid < 384) {
        int c = tid - 128;
        const unsigned* cb = cbuf + c * 4;
        unsigned w = umax32(umax32(cb[0], cb[1]), umax32(cb[2], cb[3]));
        PT[(size_t)(NCB + br) * N_PTS + bcol0 + c] = w;         // col-view slot br
    }
#undef STAGE
#undef COMPUTE
}

// =====================================================================
// Kernel 3: reduce PT -> nb[row], scanning ONLY slots written by
// construction: row-slots bc in [r>>8, 64), col-slots br in [0, 2*(r>>8)+1].
// Coverage: col-view covers j < (r>>8+1)*256, row-view j >= (r>>8)*256.
// Tie rule -> smallest global j (lexicographic (value, ~j) max).
// =====================================================================
__global__ void k_reduceP(const unsigned* __restrict__ PT, int* __restrict__ nb) {
    int r = (int)blockIdx.x * 256 + (int)threadIdx.x;
    int rb8 = r >> 8;
    u64 bst = 0;
    for (int bc = rb8; bc < NCB; ++bc) {
        unsigned p = PT[(size_t)bc * N_PTS + r];
        unsigned j = bc * 256 + 255 - (p & 255);
        bst = pmax64(bst, ((u64)(p >> 8) << 14) | (16383 - j));
    }
    int brmax = 2 * rb8 + 1;
    for (int br = 0; br <= brmax; ++br) {
        unsigned p = PT[(size_t)(NCB + br) * N_PTS + r];
        unsigned j = br * 128 + 127 - (p & 127);
        bst = pmax64(bst, ((u64)(p >> 7) << 14) | (16383 - j));
    }
    nb[r] = 16383 - (int)(bst & 16383);
}

// =====================================================================
// Kernel 4: per-row fp32 loss term: log(||x_r - x_I + 1e-6|| + 1e-8)
// =====================================================================
__global__ void k_rowloss(const float* __restrict__ x,
                          const int* __restrict__ nb,
                          float* __restrict__ rowloss) {
    int wave = (int)threadIdx.x >> 6, lane = (int)threadIdx.x & 63;
    int r = (int)blockIdx.x * 4 + wave;
    int nbi = nb[r];
    const float4* xr = (const float4*)(x + (size_t)r   * DIM);
    const float4* xn = (const float4*)(x + (size_t)nbi * DIM);
    float s = 0.f;
#pragma unroll
    for (int i = 0; i < 2; ++i) {
        float4 a = xr[lane * 2 + i];
        float4 b = xn[lane * 2 + i];
        float d0 = a.x - b.x + 1e-6f;
        float d1 = a.y - b.y + 1e-6f;
        float d2 = a.z - b.z + 1e-6f;
        float d3 = a.w - b.w + 1e-6f;
        s = fmaf(d0, d0, s); s = fmaf(d1, d1, s);
        s = fmaf(d2, d2, s); s = fmaf(d3, d3, s);
    }
#pragma unroll
    for (int m = 1; m < 64; m <<= 1) s += __shfl_xor(s, m, 64);
    if (lane == 0) rowloss[r] = logf(sqrtf(s) + 1e-8f);
}

// =====================================================================
// Kernel 5: deterministic single-block reduction -> scalar
// =====================================================================
__global__ void k_reduce(const float* __restrict__ rowloss, float* __restrict__ out) {
    __shared__ float sm[256];
    float s = 0.f;
    for (int i = (int)threadIdx.x; i < N_PTS; i += 256) s += rowloss[i];
    sm[threadIdx.x] = s;
    __syncthreads();
    for (int st = 128; st > 0; st >>= 1) {
        if ((int)threadIdx.x < st) sm[threadIdx.x] += sm[threadIdx.x + st];
        __syncthreads();
    }
    if (threadIdx.x == 0) out[0] = -0.1f * sm[0] / (float)N_PTS;
}

extern "C" void kernel_launch(void* const* d_in, const int* in_sizes, int n_in,
                              void* d_out, int out_size, void* d_ws, size_t ws_size,
                              hipStream_t stream) {
    const float* x = (const float*)d_in[0];
    float* out = (float*)d_out;
    char* ws = (char*)d_ws;

    // layout: [xq 8MB][PT (64+128)*16384 u32 = 12.6MB][nb 64KB][rowloss 64KB]
    const size_t xqB = (size_t)N_PTS * DIM;                   // 8 MB
    const size_t ptB = (size_t)(NCB + NRB) * N_PTS * 4;       // 12.58 MB
    char*     xq = ws;
    unsigned* PT = (unsigned*)(ws + xqB);
    int*      nb = (int*)(ws + xqB + ptB);
    float*    rowloss = (float*)(ws + xqB + ptB + (size_t)N_PTS * 4);

    k_quant<<<dim3(4096), dim3(256), 0, stream>>>(x, xq);
    k_gemm_argmax<<<dim3(NTILE), dim3(512), 0, stream>>>(xq, PT);
    k_reduceP<<<dim3(N_PTS / 256), dim3(256), 0, stream>>>(PT, nb);
    k_rowloss<<<dim3(N_PTS / 4), dim3(256), 0, stream>>>(x, nb, rowloss);
    k_reduce<<<dim3(1), dim3(256), 0, stream>>>(rowloss, out);
}